// Round 4
// baseline (530.004 us; speedup 1.0000x reference)
//
#include <hip/hip_runtime.h>
#include <hip/hip_fp16.h>

#define D 128
#define SCH 4096    // elements per scan block
#define NBLK 256    // blocks per level-1 distribution

typedef _Float16 half8 __attribute__((ext_vector_type(8)));
typedef float f32x4 __attribute__((ext_vector_type(4)));

// ---------------- task structs (passed by value) -----------------------------
struct HTask { const int* keys; int n; int shift; int* H; };
struct H6 { HTask t[6]; };

struct SPTask { const int* in; int n; int* part; };
struct SP6 { SPTask t[6]; };

struct SDTask { const int* in; int n; const int* part; int* out; int* total; };
struct SD6 { SDTask t[6]; };

struct ScTask { const int* k1; const int* k2; int n; int shift;
                const int* base1; const int* base2;
                int* o1; int* o2k; int* o2v; int mode; };
struct Sc4 { ScTask t[4]; };

struct CTask { const int* tmpk; const int* base; int n; int fine; int* deg; };
struct C4 { CTask t[4]; };

struct NTask { const int* outdeg; const int* indeg; float* ns; float* nd; int n; };
struct N2 { NTask t[2]; };

struct LTask { const int* tmpk; const int* tmpv; const int* base; int n;
               const int* rowptr; int shift; int fine; int* col; };
struct L2T { LTask t[2]; };

struct WPk { const float* W; _Float16* out; int K; };
struct W4 { WPk t[4]; };

struct GTask { const void* x; const float* ns; const _Float16* Wp; __half* h;
               int K; int xh; };
struct GemP { GTask t[2]; int nb0; };

struct ATask { const __half* h; const int* rowptr; const int* col;
               const float* nd; const float* b; void* out; int halfOut; };
struct AggP { ATask t[2]; int np; int ntot; };

struct MTask { const __half* x; const int* gbase; int n; const int* list; float* out; };
struct M2 { MTask t[2]; };

// ---------------- fused preprocessing ----------------------------------------

__global__ __launch_bounds__(256) void k_hist_all(H6 P) {
  HTask tk = P.t[blockIdx.y];
  __shared__ int bins[256];
  int blk = blockIdx.x, t = threadIdx.x;
  bins[t] = 0;
  __syncthreads();
  int per = (tk.n + NBLK - 1) / NBLK;
  int beg = blk * per, end = min(beg + per, tk.n);
  for (int i = beg + t; i < end; i += 256)
    atomicAdd(&bins[tk.keys[i] >> tk.shift], 1);
  __syncthreads();
  tk.H[t * NBLK + blk] = bins[t];
}

__global__ __launch_bounds__(256) void k_scan_part_all(SP6 P) {
  SPTask tk = P.t[blockIdx.y];
  int b = blockIdx.x, t = threadIdx.x;
  int base = b * SCH;
  int s = 0;
  for (int i = t; i < SCH; i += 256) {
    int idx = base + i;
    if (idx < tk.n) s += tk.in[idx];
  }
  __shared__ int red[256];
  red[t] = s;
  __syncthreads();
  for (int d = 128; d > 0; d >>= 1) {
    if (t < d) red[t] += red[t + d];
    __syncthreads();
  }
  if (t == 0) tk.part[b] = red[0];
}

__global__ __launch_bounds__(256) void k_scan_down_all(SD6 P) {
  SDTask tk = P.t[blockIdx.y];
  int b = blockIdx.x, t = threadIdx.x;
  int lane = t & 63, wid = t >> 6;
  __shared__ int wsum[4];
  if (b == 0 && t == 0 && tk.total) {
    int s = 0;
    for (int w = 0; w < (int)gridDim.x; ++w) s += tk.part[w];
    *tk.total = s;
  }
  int offset = 0;
  for (int w = 0; w < b; ++w) offset += tk.part[w];
  int base = b * SCH;
  if (base >= tk.n) return;
  int idx0 = base + t * 16;
  int v[16];
  int s = 0;
#pragma unroll
  for (int i = 0; i < 16; ++i) {
    int idx = idx0 + i;
    v[i] = (idx < tk.n) ? tk.in[idx] : 0;
    s += v[i];
  }
  int inc = s;
  for (int d = 1; d < 64; d <<= 1) {
    int u = __shfl_up(inc, d, 64);
    if (lane >= d) inc += u;
  }
  if (lane == 63) wsum[wid] = inc;
  __syncthreads();
  int woff = 0;
  for (int w = 0; w < wid; ++w) woff += wsum[w];
  int ex = offset + woff + inc - s;
#pragma unroll
  for (int i = 0; i < 16; ++i) {
    int idx = idx0 + i;
    if (idx < tk.n) tk.out[idx] = ex;
    ex += v[i];
  }
}

__global__ __launch_bounds__(256) void k_scatter_all(Sc4 P) {
  ScTask tk = P.t[blockIdx.y];
  __shared__ int curA[256], curB[256];
  int blk = blockIdx.x, t = threadIdx.x;
  curA[t] = tk.base1[t * NBLK + blk];
  if (tk.mode == 0) curB[t] = tk.base2[t * NBLK + blk];
  __syncthreads();
  int per = (tk.n + NBLK - 1) / NBLK;
  int beg = blk * per, end = min(beg + per, tk.n);
  if (tk.mode == 0) {
    for (int i = beg + t; i < end; i += 256) {
      int s = tk.k1[i], d = tk.k2[i];
      int pa = atomicAdd(&curA[s >> tk.shift], 1);
      tk.o1[pa] = s;
      int pb = atomicAdd(&curB[d >> tk.shift], 1);
      tk.o2k[pb] = d;
      tk.o2v[pb] = s;
    }
  } else {
    for (int i = beg + t; i < end; i += 256) {
      int pa = atomicAdd(&curA[tk.k1[i] >> tk.shift], 1);
      tk.o1[pa] = i;
    }
  }
}

__global__ __launch_bounds__(256) void k_l2count_all(C4 P) {
  CTask tk = P.t[blockIdx.y];
  __shared__ int bins[512];
  int b = blockIdx.x, t = threadIdx.x;
  for (int f = t; f < tk.fine; f += 256) bins[f] = 0;
  __syncthreads();
  int beg = tk.base[b * NBLK];
  int end = (b == NBLK - 1) ? tk.n : tk.base[(b + 1) * NBLK];
  for (int i = beg + t; i < end; i += 256)
    atomicAdd(&bins[tk.tmpk[i] & (tk.fine - 1)], 1);
  __syncthreads();
  for (int f = t; f < tk.fine; f += 256)
    tk.deg[b * tk.fine + f] = bins[f];
}

__global__ __launch_bounds__(256) void k_norms_all(N2 P) {
  NTask tk = P.t[blockIdx.y];
  int i = blockIdx.x * blockDim.x + threadIdx.x;
  if (i < tk.n) {
    tk.ns[i] = rsqrtf(fmaxf((float)tk.outdeg[i], 1.f));
    tk.nd[i] = rsqrtf(fmaxf((float)tk.indeg[i], 1.f));
  }
}

__global__ __launch_bounds__(256) void k_l2scatter_all(L2T P) {
  LTask tk = P.t[blockIdx.y];
  __shared__ int cur[512];
  int b = blockIdx.x, t = threadIdx.x;
  int v0 = b << tk.shift;
  for (int f = t; f < tk.fine; f += 256) cur[f] = tk.rowptr[v0 + f];
  __syncthreads();
  int beg = tk.base[b * NBLK];
  int end = (b == NBLK - 1) ? tk.n : tk.base[(b + 1) * NBLK];
  for (int i = beg + t; i < end; i += 256) {
    int pos = atomicAdd(&cur[tk.tmpk[i] & (tk.fine - 1)], 1);
    tk.col[pos] = tk.tmpv[i];
  }
}

// ---------------- towers ------------------------------------------------------

// Pack W (K x 128, fp32) into MFMA-B-fragment order, fp16:
//   out[((kc*8+nt)*64 + lane)*8 + e] = W[kc*32 + (lane>>4)*8 + e][nt*16 + (lane&15)]
__global__ __launch_bounds__(256) void k_wpack(W4 P) {
  WPk tk = P.t[blockIdx.y];
  int f = blockIdx.x;                       // fragment id 0..31
  int kch = (tk.K + 31) >> 5;
  if (f >= (kch << 3)) return;
  int kc = f >> 3, nt = f & 7;
  int t = threadIdx.x;
  int l = t & 63, e0 = (t >> 6) << 1;       // each thread handles 2 e-slots
  int col = (nt << 4) + (l & 15);
  int kb = (kc << 5) + ((l >> 4) << 3);
#pragma unroll
  for (int e = e0; e < e0 + 2; ++e) {
    int k = kb + e;
    float v = (k < tk.K) ? tk.W[(size_t)k * D + col] : 0.f;
    tk.out[(((size_t)f * 64 + l) << 3) + e] = (_Float16)v;
  }
}

// h[v,:] = fp16( ns[v] * (x[v,:] @ W) ) via mfma_f32_16x16x32_f16.
// 128 nodes x 128 feats per 256-thread block (4 waves). Wave w owns rows
// [w*32, w*32+32): 2 M-tiles x 8 N-tiles of 16x16, K swept in 32-chunks.
__global__ __launch_bounds__(256) void k_nl_gemm(GemP P) {
  __shared__ __align__(16) _Float16 Bs[32 * 64 * 8];   // 32 KB
  int bx = blockIdx.x;
  GTask tk;
  int v0;
  if (bx < P.nb0) { tk = P.t[0]; v0 = bx * 128; }
  else            { tk = P.t[1]; v0 = (bx - P.nb0) * 128; }
  const int K = tk.K;
  const int kch = (K + 31) >> 5;            // 4 (K=128) or 3 (K=74)
  int t = threadIdx.x, w = t >> 6, l = t & 63;

  // stage packed W into LDS (linear copy)
  {
    const uint4* src = (const uint4*)tk.Wp;
    uint4* dst = (uint4*)Bs;
    int n16 = kch << 9;                     // kch*8 frags * 64 lanes
    for (int i = t; i < n16; i += 256) dst[i] = src[i];
  }
  __syncthreads();

  int row = l & 15;
  int ks = (l >> 4) << 3;                   // k offset within 32-chunk
  int m0 = v0 + (w << 5);
  const float* xf0 = nullptr; const float* xf1 = nullptr;
  const _Float16* xh0 = nullptr; const _Float16* xh1 = nullptr;
  if (tk.xh) {
    xh0 = (const _Float16*)tk.x + (size_t)(m0 + row) * D + ks;
    xh1 = xh0 + (size_t)16 * D;
  } else {
    xf0 = (const float*)tk.x + (size_t)(m0 + row) * K + ks;
    xf1 = xf0 + (size_t)16 * K;
  }

  f32x4 acc[2][8];
  f32x4 zero = {0.f, 0.f, 0.f, 0.f};
#pragma unroll
  for (int i = 0; i < 2; ++i)
#pragma unroll
    for (int j = 0; j < 8; ++j) acc[i][j] = zero;

  for (int kc = 0; kc < kch; ++kc) {
    half8 a0, a1;
    if (tk.xh) {                            // fp16 input, direct 16B fragments
      a0 = *(const half8*)(xh0 + (kc << 5));
      a1 = *(const half8*)(xh1 + (kc << 5));
    } else if (K == D) {                    // fp32 dense K=128, 16B-aligned
      float4 p0 = *(const float4*)(xf0 + (kc << 5));
      float4 p1 = *(const float4*)(xf0 + (kc << 5) + 4);
      float4 q0 = *(const float4*)(xf1 + (kc << 5));
      float4 q1 = *(const float4*)(xf1 + (kc << 5) + 4);
      a0[0] = (_Float16)p0.x; a0[1] = (_Float16)p0.y;
      a0[2] = (_Float16)p0.z; a0[3] = (_Float16)p0.w;
      a0[4] = (_Float16)p1.x; a0[5] = (_Float16)p1.y;
      a0[6] = (_Float16)p1.z; a0[7] = (_Float16)p1.w;
      a1[0] = (_Float16)q0.x; a1[1] = (_Float16)q0.y;
      a1[2] = (_Float16)q0.z; a1[3] = (_Float16)q0.w;
      a1[4] = (_Float16)q1.x; a1[5] = (_Float16)q1.y;
      a1[6] = (_Float16)q1.z; a1[7] = (_Float16)q1.w;
    } else {                                // K=74: guarded scalar, zero-padded
#pragma unroll
      for (int e = 0; e < 8; ++e) {
        int k = (kc << 5) + ks + e;
        a0[e] = (k < K) ? (_Float16)xf0[(kc << 5) + e] : (_Float16)0.f;
        a1[e] = (k < K) ? (_Float16)xf1[(kc << 5) + e] : (_Float16)0.f;
      }
    }
#pragma unroll
    for (int nt = 0; nt < 8; ++nt) {
      half8 b = *(const half8*)&Bs[(size_t)((((kc << 3) + nt) << 6) + l) << 3];
      acc[0][nt] = __builtin_amdgcn_mfma_f32_16x16x32_f16(a0, b, acc[0][nt], 0, 0, 0);
      acc[1][nt] = __builtin_amdgcn_mfma_f32_16x16x32_f16(a1, b, acc[1][nt], 0, 0, 0);
    }
  }

  // epilogue: C/D layout col=lane&15, row=(lane>>4)*4+reg
  int rr = (l >> 4) << 2;
  int c0 = l & 15;
#pragma unroll
  for (int mt = 0; mt < 2; ++mt) {
    int vb = m0 + (mt << 4) + rr;
    float s0 = tk.ns[vb], s1 = tk.ns[vb + 1];
    float s2 = tk.ns[vb + 2], s3 = tk.ns[vb + 3];
#pragma unroll
    for (int nt = 0; nt < 8; ++nt) {
      __half* hp = tk.h + (size_t)vb * D + (nt << 4) + c0;
      hp[0]     = __float2half_rn(acc[mt][nt][0] * s0);
      hp[D]     = __float2half_rn(acc[mt][nt][1] * s1);
      hp[2 * D] = __float2half_rn(acc[mt][nt][2] * s2);
      hp[3 * D] = __float2half_rn(acc[mt][nt][3] * s3);
    }
  }
}

// ---- aggregation: wave-per-node (grid-stride), 16 lanes x 8 feats (16B),
//      4 rows/instr, 32 edges per window (8 gathers in flight per lane) ------
__global__ __launch_bounds__(256) void k_aggregate(AggP P) {
  int wid = threadIdx.x >> 6;
  int lane = threadIdx.x & 63;
  int f0 = (lane & 15) * 8;
  int rsel = lane >> 4;
  int nw = (int)gridDim.x * 4;

  for (int gv = blockIdx.x * 4 + wid; gv < P.ntot; gv += nw) {
    ATask tk;
    int v;
    if (gv < P.np) { tk = P.t[0]; v = gv; }
    else           { tk = P.t[1]; v = gv - P.np; }
    int beg = tk.rowptr[v], end = tk.rowptr[v + 1];
    const __half* h = tk.h;
    const int* col = tk.col;

    float acc[8];
#pragma unroll
    for (int k = 0; k < 8; ++k) acc[k] = 0.f;

    for (int j = beg; j < end; j += 32) {
      int cc[8];
#pragma unroll
      for (int q = 0; q < 8; ++q) {
        int jj = j + 4 * q + rsel;
        cc[q] = (jj < end) ? col[jj] : -1;
      }
#pragma unroll
      for (int q = 0; q < 8; ++q) {
        if (cc[q] >= 0) {
          uint4 r = *(const uint4*)&h[(size_t)cc[q] * D + f0];
          const __half2* p = (const __half2*)&r;
#pragma unroll
          for (int k = 0; k < 4; ++k) {
            float2 f = __half22float2(p[k]);
            acc[2 * k] += f.x; acc[2 * k + 1] += f.y;
          }
        }
      }
    }

#pragma unroll
    for (int k = 0; k < 8; ++k) {
      acc[k] += __shfl_down(acc[k], 32, 64);
      acc[k] += __shfl_down(acc[k], 16, 64);
    }

    if (rsel == 0) {
      float s = tk.nd[v];
      float4 b0 = *(const float4*)&tk.b[f0];
      float4 b1 = *(const float4*)&tk.b[f0 + 4];
      float r[8];
      r[0] = fmaxf(fmaf(acc[0], s, b0.x), 0.f);
      r[1] = fmaxf(fmaf(acc[1], s, b0.y), 0.f);
      r[2] = fmaxf(fmaf(acc[2], s, b0.z), 0.f);
      r[3] = fmaxf(fmaf(acc[3], s, b0.w), 0.f);
      r[4] = fmaxf(fmaf(acc[4], s, b1.x), 0.f);
      r[5] = fmaxf(fmaf(acc[5], s, b1.y), 0.f);
      r[6] = fmaxf(fmaf(acc[6], s, b1.z), 0.f);
      r[7] = fmaxf(fmaf(acc[7], s, b1.w), 0.f);
      if (tk.halfOut) {
        union { __half2 h2[4]; uint4 u; } pk;
#pragma unroll
        for (int k = 0; k < 4; ++k) {
          pk.h2[k].x = __float2half_rn(r[2 * k]);
          pk.h2[k].y = __float2half_rn(r[2 * k + 1]);
        }
        *(uint4*)&((__half*)tk.out)[(size_t)v * D + f0] = pk.u;
      } else {
        float4 o0 = {r[0], r[1], r[2], r[3]};
        float4 o1 = {r[4], r[5], r[6], r[7]};
        *(float4*)&((float*)tk.out)[(size_t)v * D + f0] = o0;
        *(float4*)&((float*)tk.out)[(size_t)v * D + f0 + 4] = o1;
      }
    }
  }
}

__device__ __forceinline__ void acc_half4(float4& a, const __half* p) {
  uint2 r = *(const uint2*)p;
  __half2 q0 = *(__half2*)&r.x;
  __half2 q1 = *(__half2*)&r.y;
  float2 f0 = __half22float2(q0);
  float2 f1 = __half22float2(q1);
  a.x += f0.x; a.y += f0.y; a.z += f1.x; a.w += f1.y;
}

__global__ __launch_bounds__(256) void k_seg_mean(M2 P) {
  MTask tk = P.t[blockIdx.y];
  int g = blockIdx.x, t = threadIdx.x;
  int slot = t >> 5;
  int c = (t & 31) * 4;
  int beg = tk.gbase[g * NBLK];
  int end = (g == (int)gridDim.x - 1) ? tk.n : tk.gbase[(g + 1) * NBLK];
  const __half* x = tk.x;
  const int* list = tk.list;

  float4 a0 = make_float4(0.f, 0.f, 0.f, 0.f);
  float4 a1 = make_float4(0.f, 0.f, 0.f, 0.f);
  int j = beg + slot;
  for (; j + 8 < end; j += 16) {
    int s0 = list[j], s1 = list[j + 8];
    acc_half4(a0, x + (size_t)s0 * D + c);
    acc_half4(a1, x + (size_t)s1 * D + c);
  }
  if (j < end)
    acc_half4(a0, x + (size_t)list[j] * D + c);
  a0.x += a1.x; a0.y += a1.y; a0.z += a1.z; a0.w += a1.w;

  a0.x += __shfl_down(a0.x, 32, 64);
  a0.y += __shfl_down(a0.y, 32, 64);
  a0.z += __shfl_down(a0.z, 32, 64);
  a0.w += __shfl_down(a0.w, 32, 64);

  __shared__ float sred[4][32 * 4];
  int wid = t >> 6, lane = t & 63;
  if (lane < 32) *(float4*)&sred[wid][lane * 4] = a0;
  __syncthreads();
  if (t < 32) {
    float4 s0 = *(const float4*)&sred[0][t * 4];
    float4 s1 = *(const float4*)&sred[1][t * 4];
    float4 s2 = *(const float4*)&sred[2][t * 4];
    float4 s3 = *(const float4*)&sred[3][t * 4];
    float inv = 1.f / fmaxf((float)(end - beg), 1.f);
    float4 r;
    r.x = (s0.x + s1.x + s2.x + s3.x) * inv;
    r.y = (s0.y + s1.y + s2.y + s3.y) * inv;
    r.z = (s0.z + s1.z + s2.z + s3.z) * inv;
    r.w = (s0.w + s1.w + s2.w + s3.w) * inv;
    *(float4*)&tk.out[(size_t)g * D + c] = r;
  }
}

__global__ void k_mlp(const float* __restrict__ cg, const float* __restrict__ pg,
                      const float* __restrict__ Wf1, const float* __restrict__ bf1,
                      const float* __restrict__ Wf2, const float* __restrict__ bf2,
                      float* __restrict__ out) {
  __shared__ float xs[256];
  __shared__ float red[128];
  int b = blockIdx.x, t = threadIdx.x;
  xs[t] = cg[b * D + t];
  xs[128 + t] = pg[b * D + t];
  __syncthreads();
  float acc = bf1[t];
  for (int k = 0; k < 256; ++k) acc = fmaf(xs[k], Wf1[k * D + t], acc);
  float hv = fmaxf(acc, 0.f);
  red[t] = hv * Wf2[t];
  for (int d = 64; d > 0; d >>= 1) {
    __syncthreads();
    if (t < d) red[t] += red[t + d];
  }
  if (t == 0) out[b] = red[0] + bf2[0];
}

// ---------------- launch ------------------------------------------------------

extern "C" void kernel_launch(void* const* d_in, const int* in_sizes, int n_in,
                              void* d_out, int out_size, void* d_ws, size_t ws_size,
                              hipStream_t stream) {
  const float* compound_feat = (const float*)d_in[0];
  const float* protein_feat  = (const float*)d_in[1];
  const int* c_src = (const int*)d_in[2];
  const int* c_dst = (const int*)d_in[3];
  const int* p_src = (const int*)d_in[4];
  const int* p_dst = (const int*)d_in[5];
  const int* c_gid = (const int*)d_in[6];
  const int* p_gid = (const int*)d_in[7];
  const float* Wc1 = (const float*)d_in[8];  const float* bc1 = (const float*)d_in[9];
  const float* Wc2 = (const float*)d_in[10]; const float* bc2 = (const float*)d_in[11];
  const float* Wp1 = (const float*)d_in[12]; const float* bp1 = (const float*)d_in[13];
  const float* Wp2 = (const float*)d_in[14]; const float* bp2 = (const float*)d_in[15];
  const float* Wf1 = (const float*)d_in[16]; const float* bf1 = (const float*)d_in[17];
  const float* Wf2 = (const float*)d_in[18]; const float* bf2 = (const float*)d_in[19];
  float* out = (float*)d_out;

  const int EC = in_sizes[2], EP = in_sizes[4];
  const int NC = in_sizes[6], NP = in_sizes[7];
  const int B  = out_size;
  const int KC = in_sizes[0] / NC;                 // 74
  const int cshift = __builtin_ctz(NC / 256), cfine = NC / 256;
  const int pshift = __builtin_ctz(NP / 256), pfine = NP / 256;
  const int HN = 256 * NBLK;

  char* ws = (char*)d_ws;
  size_t off = 0;
  auto alloc = [&](size_t bytes) -> void* {
    void* p = ws + off;
    off += (bytes + 255) & ~(size_t)255;
    return p;
  };

  int* H0 = (int*)alloc((size_t)HN * 4);
  int* H1 = (int*)alloc((size_t)HN * 4);
  int* H2 = (int*)alloc((size_t)HN * 4);
  int* H3 = (int*)alloc((size_t)HN * 4);
  int* H4 = (int*)alloc((size_t)HN * 4);
  int* H5 = (int*)alloc((size_t)HN * 4);
  int* partH = (int*)alloc((size_t)6 * 32 * 4);
  int* partD = (int*)alloc((size_t)2 * 32 * 4);
  int* tmps_c = (int*)alloc((size_t)EC * 4);
  int* tmpd_c = (int*)alloc((size_t)EC * 4);
  int* tmpv_c = (int*)alloc((size_t)EC * 4);
  int* tmps_p = (int*)alloc((size_t)EP * 4);
  int* tmpd_p = (int*)alloc((size_t)EP * 4);
  int* tmpv_p = (int*)alloc((size_t)EP * 4);
  int* c_outdeg = (int*)alloc((size_t)NC * 4);
  int* c_indeg  = (int*)alloc((size_t)NC * 4);
  int* p_outdeg = (int*)alloc((size_t)NP * 4);
  int* p_indeg  = (int*)alloc((size_t)NP * 4);
  float* c_ns = (float*)alloc((size_t)NC * 4);
  float* c_nd = (float*)alloc((size_t)NC * 4);
  float* p_ns = (float*)alloc((size_t)NP * 4);
  float* p_nd = (float*)alloc((size_t)NP * 4);
  int* c_rowptr = (int*)alloc((size_t)(NC + 1) * 4);
  int* p_rowptr = (int*)alloc((size_t)(NP + 1) * 4);
  int* c_col   = (int*)alloc((size_t)EC * 4);
  int* p_col   = (int*)alloc((size_t)EP * 4);
  int* cg_list = (int*)alloc((size_t)NC * 4);
  int* pg_list = (int*)alloc((size_t)NP * 4);
  __half* c_h  = (__half*)alloc((size_t)NC * D * 2);
  __half* c_m1 = (__half*)alloc((size_t)NC * D * 2);
  __half* c_m2 = (__half*)alloc((size_t)NC * D * 2);
  __half* p_h  = (__half*)alloc((size_t)NP * D * 2);
  __half* p_m1 = (__half*)alloc((size_t)NP * D * 2);
  __half* p_m2 = (__half*)alloc((size_t)NP * D * 2);
  float* cg = (float*)alloc((size_t)B * D * 4);
  float* pg = (float*)alloc((size_t)B * D * 4);
  _Float16* wp_p1 = (_Float16*)alloc((size_t)32 * 1024);
  _Float16* wp_c1 = (_Float16*)alloc((size_t)32 * 1024);
  _Float16* wp_p2 = (_Float16*)alloc((size_t)32 * 1024);
  _Float16* wp_c2 = (_Float16*)alloc((size_t)32 * 1024);
  (void)ws_size; (void)n_in;

  // 0) pack the four W matrices into fp16 MFMA fragment order (independent)
  {
    W4 PW = {{{Wp1, wp_p1, D}, {Wc1, wp_c1, KC}, {Wp2, wp_p2, D}, {Wc2, wp_c2, D}}};
    k_wpack<<<dim3(32, 4), 256, 0, stream>>>(PW);
  }
  // 1) all six 256-bin histograms
  {
    H6 P = {{{c_src, EC, cshift, H0}, {c_dst, EC, cshift, H1}, {c_gid, NC, 0, H2},
             {p_src, EP, pshift, H3}, {p_dst, EP, pshift, H4}, {p_gid, NP, 0, H5}}};
    k_hist_all<<<dim3(NBLK, 6), 256, 0, stream>>>(P);
  }
  // 2) scan the six H arrays in place
  {
    SP6 Pp = {{{H0, HN, partH + 0}, {H1, HN, partH + 32}, {H2, HN, partH + 64},
               {H3, HN, partH + 96}, {H4, HN, partH + 128}, {H5, HN, partH + 160}}};
    k_scan_part_all<<<dim3(16, 6), 256, 0, stream>>>(Pp);
    SD6 Pd = {{{H0, HN, partH + 0, H0, nullptr}, {H1, HN, partH + 32, H1, nullptr},
               {H2, HN, partH + 64, H2, nullptr}, {H3, HN, partH + 96, H3, nullptr},
               {H4, HN, partH + 128, H4, nullptr}, {H5, HN, partH + 160, H5, nullptr}}};
    k_scan_down_all<<<dim3(16, 6), 256, 0, stream>>>(Pd);
  }
  // 3) all level-1 scatters
  {
    Sc4 P = {{{c_src, c_dst, EC, cshift, H0, H1, tmps_c, tmpd_c, tmpv_c, 0},
              {p_src, p_dst, EP, pshift, H3, H4, tmps_p, tmpd_p, tmpv_p, 0},
              {c_gid, nullptr, NC, 0, H2, nullptr, cg_list, nullptr, nullptr, 1},
              {p_gid, nullptr, NP, 0, H5, nullptr, pg_list, nullptr, nullptr, 1}}};
    k_scatter_all<<<dim3(NBLK, 4), 256, 0, stream>>>(P);
  }
  // 4) level-2 counts -> degrees
  {
    C4 P = {{{tmps_c, H0, EC, cfine, c_outdeg}, {tmpd_c, H1, EC, cfine, c_indeg},
             {tmps_p, H3, EP, pfine, p_outdeg}, {tmpd_p, H4, EP, pfine, p_indeg}}};
    k_l2count_all<<<dim3(NBLK, 4), 256, 0, stream>>>(P);
  }
  // 5) scan indegrees -> rowptr
  {
    SP6 Pp; Pp.t[0] = {c_indeg, NC, partD + 0}; Pp.t[1] = {p_indeg, NP, partD + 32};
    Pp.t[2] = Pp.t[3] = Pp.t[4] = Pp.t[5] = SPTask{c_indeg, 0, partD + 0};
    k_scan_part_all<<<dim3(32, 2), 256, 0, stream>>>(Pp);
    SD6 Pd; Pd.t[0] = {c_indeg, NC, partD + 0, c_rowptr, c_rowptr + NC};
    Pd.t[1] = {p_indeg, NP, partD + 32, p_rowptr, p_rowptr + NP};
    Pd.t[2] = Pd.t[3] = Pd.t[4] = Pd.t[5] = Pd.t[0];
    k_scan_down_all<<<dim3(32, 2), 256, 0, stream>>>(Pd);
  }
  // 6) norms
  {
    N2 P = {{{c_outdeg, c_indeg, c_ns, c_nd, NC}, {p_outdeg, p_indeg, p_ns, p_nd, NP}}};
    k_norms_all<<<dim3((NP + 255) / 256, 2), 256, 0, stream>>>(P);
  }
  // 7) level-2 scatter -> CSR col
  {
    L2T P = {{{tmpd_c, tmpv_c, H1, EC, c_rowptr, cshift, cfine, c_col},
              {tmpd_p, tmpv_p, H4, EP, p_rowptr, pshift, pfine, p_col}}};
    k_l2scatter_all<<<dim3(NBLK, 2), 256, 0, stream>>>(P);
  }

  // ---- towers (flattened grids: protein first) ----
  const int gnb = NP / 128 + NC / 128;
  const int ntot = NP + NC;
  const int anb = min((ntot + 3) / 4, 8192);   // grid-stride persistent waves
  {
    GemP P = {{{protein_feat, p_ns, wp_p1, p_h, D, 0},
               {compound_feat, c_ns, wp_c1, c_h, KC, 0}}, NP / 128};
    k_nl_gemm<<<gnb, 256, 0, stream>>>(P);
  }
  {
    AggP P = {{{p_h, p_rowptr, p_col, p_nd, bp1, p_m1, 1},
               {c_h, c_rowptr, c_col, c_nd, bc1, c_m1, 1}}, NP, ntot};
    k_aggregate<<<anb, 256, 0, stream>>>(P);
  }
  {
    GemP P = {{{p_m1, p_ns, wp_p2, p_h, D, 1}, {c_m1, c_ns, wp_c2, c_h, D, 1}}, NP / 128};
    k_nl_gemm<<<gnb, 256, 0, stream>>>(P);
  }
  {
    AggP P = {{{p_h, p_rowptr, p_col, p_nd, bp2, p_m2, 1},
               {c_h, c_rowptr, c_col, c_nd, bc2, c_m2, 1}}, NP, ntot};
    k_aggregate<<<anb, 256, 0, stream>>>(P);
  }
  {
    M2 P = {{{c_m2, H2, NC, cg_list, cg}, {p_m2, H5, NP, pg_list, pg}}};
    k_seg_mean<<<dim3(B, 2), 256, 0, stream>>>(P);
  }

  k_mlp<<<B, D, 0, stream>>>(cg, pg, Wf1, bf1, Wf2, bf2, out);
}

// Round 5
// 518.715 us; speedup vs baseline: 1.0218x; 1.0218x over previous
//
#include <hip/hip_runtime.h>
#include <hip/hip_fp16.h>

#define D 128
#define SCH 4096    // elements per scan block
#define NBLK 256    // blocks per level-1 distribution

typedef _Float16 half8 __attribute__((ext_vector_type(8)));
typedef float f32x4 __attribute__((ext_vector_type(4)));

// ---------------- task structs (passed by value) -----------------------------
struct HTask { const int* keys; int n; int shift; int* H; };
struct H6 { HTask t[6]; };

struct SPTask { const int* in; int n; int* part; };
struct SP6 { SPTask t[6]; };

struct SDTask { const int* in; int n; const int* part; int* out; int* total; };
struct SD6 { SDTask t[6]; };

struct ScTask { const int* k1; const int* k2; int n; int shift;
                const int* base1; const int* base2;
                int* o1; int* o2k; int* o2v; int mode; };
struct Sc4 { ScTask t[4]; };

struct CTask { const int* tmpk; const int* base; int n; int fine; int* deg; };
struct C4 { CTask t[4]; };

struct NTask { const int* outdeg; const int* indeg; float* ns; float* nd; int n; };
struct N2 { NTask t[2]; };

struct LTask { const int* tmpk; const int* tmpv; const int* base; int n;
               const int* rowptr; int shift; int fine; int* col; };
struct L2T { LTask t[2]; };

struct WPk { const float* W; _Float16* out; int K; };
struct W4 { WPk t[4]; };

struct GTask { const void* x; const float* ns; const _Float16* Wp; __half* h;
               int K; int xh; };
struct GemP { GTask t[2]; int nb0; };

struct ATask { const __half* h; const int* rowptr; const int* col;
               const float* nd; const float* b; const int* perm;
               void* out; int halfOut; };
struct AggP { ATask t[2]; int np; int ntot; };

struct MTask { const __half* x; const int* gbase; int n; float* out; };
struct M2 { MTask t[2]; };

// ---------------- fused preprocessing ----------------------------------------

__global__ __launch_bounds__(256) void k_hist_all(H6 P) {
  HTask tk = P.t[blockIdx.y];
  __shared__ int bins[256];
  int blk = blockIdx.x, t = threadIdx.x;
  bins[t] = 0;
  __syncthreads();
  int per = (tk.n + NBLK - 1) / NBLK;
  int beg = blk * per, end = min(beg + per, tk.n);
  for (int i = beg + t; i < end; i += 256)
    atomicAdd(&bins[tk.keys[i] >> tk.shift], 1);
  __syncthreads();
  tk.H[t * NBLK + blk] = bins[t];
}

__global__ __launch_bounds__(256) void k_scan_part_all(SP6 P) {
  SPTask tk = P.t[blockIdx.y];
  int b = blockIdx.x, t = threadIdx.x;
  int base = b * SCH;
  int s = 0;
  for (int i = t; i < SCH; i += 256) {
    int idx = base + i;
    if (idx < tk.n) s += tk.in[idx];
  }
  __shared__ int red[256];
  red[t] = s;
  __syncthreads();
  for (int d = 128; d > 0; d >>= 1) {
    if (t < d) red[t] += red[t + d];
    __syncthreads();
  }
  if (t == 0) tk.part[b] = red[0];
}

__global__ __launch_bounds__(256) void k_scan_down_all(SD6 P) {
  SDTask tk = P.t[blockIdx.y];
  int b = blockIdx.x, t = threadIdx.x;
  int lane = t & 63, wid = t >> 6;
  __shared__ int wsum[4];
  if (b == 0 && t == 0 && tk.total) {
    int s = 0;
    for (int w = 0; w < (int)gridDim.x; ++w) s += tk.part[w];
    *tk.total = s;
  }
  int offset = 0;
  for (int w = 0; w < b; ++w) offset += tk.part[w];
  int base = b * SCH;
  if (base >= tk.n) return;
  int idx0 = base + t * 16;
  int v[16];
  int s = 0;
#pragma unroll
  for (int i = 0; i < 16; ++i) {
    int idx = idx0 + i;
    v[i] = (idx < tk.n) ? tk.in[idx] : 0;
    s += v[i];
  }
  int inc = s;
  for (int d = 1; d < 64; d <<= 1) {
    int u = __shfl_up(inc, d, 64);
    if (lane >= d) inc += u;
  }
  if (lane == 63) wsum[wid] = inc;
  __syncthreads();
  int woff = 0;
  for (int w = 0; w < wid; ++w) woff += wsum[w];
  int ex = offset + woff + inc - s;
#pragma unroll
  for (int i = 0; i < 16; ++i) {
    int idx = idx0 + i;
    if (idx < tk.n) tk.out[idx] = ex;
    ex += v[i];
  }
}

__global__ __launch_bounds__(256) void k_scatter_all(Sc4 P) {
  ScTask tk = P.t[blockIdx.y];
  __shared__ int curA[256], curB[256];
  int blk = blockIdx.x, t = threadIdx.x;
  curA[t] = tk.base1[t * NBLK + blk];
  if (tk.mode == 0) curB[t] = tk.base2[t * NBLK + blk];
  __syncthreads();
  int per = (tk.n + NBLK - 1) / NBLK;
  int beg = blk * per, end = min(beg + per, tk.n);
  if (tk.mode == 0) {
    for (int i = beg + t; i < end; i += 256) {
      int s = tk.k1[i], d = tk.k2[i];
      int pa = atomicAdd(&curA[s >> tk.shift], 1);
      tk.o1[pa] = s;
      int pb = atomicAdd(&curB[d >> tk.shift], 1);
      tk.o2k[pb] = d;
      tk.o2v[pb] = s;
    }
  } else {
    // mode 1: emit inverse permutation perm[i] = graph-sorted position of i
    for (int i = beg + t; i < end; i += 256) {
      int pa = atomicAdd(&curA[tk.k1[i] >> tk.shift], 1);
      tk.o1[i] = pa;
    }
  }
}

__global__ __launch_bounds__(256) void k_l2count_all(C4 P) {
  CTask tk = P.t[blockIdx.y];
  __shared__ int bins[512];
  int b = blockIdx.x, t = threadIdx.x;
  for (int f = t; f < tk.fine; f += 256) bins[f] = 0;
  __syncthreads();
  int beg = tk.base[b * NBLK];
  int end = (b == NBLK - 1) ? tk.n : tk.base[(b + 1) * NBLK];
  for (int i = beg + t; i < end; i += 256)
    atomicAdd(&bins[tk.tmpk[i] & (tk.fine - 1)], 1);
  __syncthreads();
  for (int f = t; f < tk.fine; f += 256)
    tk.deg[b * tk.fine + f] = bins[f];
}

__global__ __launch_bounds__(256) void k_norms_all(N2 P) {
  NTask tk = P.t[blockIdx.y];
  int i = blockIdx.x * blockDim.x + threadIdx.x;
  if (i < tk.n) {
    tk.ns[i] = rsqrtf(fmaxf((float)tk.outdeg[i], 1.f));
    tk.nd[i] = rsqrtf(fmaxf((float)tk.indeg[i], 1.f));
  }
}

__global__ __launch_bounds__(256) void k_l2scatter_all(L2T P) {
  LTask tk = P.t[blockIdx.y];
  __shared__ int cur[512];
  int b = blockIdx.x, t = threadIdx.x;
  int v0 = b << tk.shift;
  for (int f = t; f < tk.fine; f += 256) cur[f] = tk.rowptr[v0 + f];
  __syncthreads();
  int beg = tk.base[b * NBLK];
  int end = (b == NBLK - 1) ? tk.n : tk.base[(b + 1) * NBLK];
  for (int i = beg + t; i < end; i += 256) {
    int pos = atomicAdd(&cur[tk.tmpk[i] & (tk.fine - 1)], 1);
    tk.col[pos] = tk.tmpv[i];
  }
}

// ---------------- towers ------------------------------------------------------

// Pack W (K x 128, fp32) into MFMA-B-fragment order, fp16:
//   out[((kc*8+nt)*64 + lane)*8 + e] = W[kc*32 + (lane>>4)*8 + e][nt*16 + (lane&15)]
__global__ __launch_bounds__(256) void k_wpack(W4 P) {
  WPk tk = P.t[blockIdx.y];
  int f = blockIdx.x;                       // fragment id 0..31
  int kch = (tk.K + 31) >> 5;
  if (f >= (kch << 3)) return;
  int kc = f >> 3, nt = f & 7;
  int t = threadIdx.x;
  int l = t & 63, e0 = (t >> 6) << 1;       // each thread handles 2 e-slots
  int col = (nt << 4) + (l & 15);
  int kb = (kc << 5) + ((l >> 4) << 3);
#pragma unroll
  for (int e = e0; e < e0 + 2; ++e) {
    int k = kb + e;
    float v = (k < tk.K) ? tk.W[(size_t)k * D + col] : 0.f;
    tk.out[(((size_t)f * 64 + l) << 3) + e] = (_Float16)v;
  }
}

// h[v,:] = fp16( ns[v] * (x[v,:] @ W) ) via mfma_f32_16x16x32_f16.
// 128 nodes x 128 feats per 256-thread block (4 waves). Wave w owns rows
// [w*32, w*32+32): 2 M-tiles x 8 N-tiles of 16x16, K swept in 32-chunks.
__global__ __launch_bounds__(256) void k_nl_gemm(GemP P) {
  __shared__ __align__(16) _Float16 Bs[32 * 64 * 8];   // 32 KB
  int bx = blockIdx.x;
  GTask tk;
  int v0;
  if (bx < P.nb0) { tk = P.t[0]; v0 = bx * 128; }
  else            { tk = P.t[1]; v0 = (bx - P.nb0) * 128; }
  const int K = tk.K;
  const int kch = (K + 31) >> 5;            // 4 (K=128) or 3 (K=74)
  int t = threadIdx.x, w = t >> 6, l = t & 63;

  // stage packed W into LDS (linear copy)
  {
    const uint4* src = (const uint4*)tk.Wp;
    uint4* dst = (uint4*)Bs;
    int n16 = kch << 9;                     // kch*8 frags * 64 lanes
    for (int i = t; i < n16; i += 256) dst[i] = src[i];
  }
  __syncthreads();

  int row = l & 15;
  int ks = (l >> 4) << 3;                   // k offset within 32-chunk
  int m0 = v0 + (w << 5);
  const float* xf0 = nullptr; const float* xf1 = nullptr;
  const _Float16* xh0 = nullptr; const _Float16* xh1 = nullptr;
  if (tk.xh) {
    xh0 = (const _Float16*)tk.x + (size_t)(m0 + row) * D + ks;
    xh1 = xh0 + (size_t)16 * D;
  } else {
    xf0 = (const float*)tk.x + (size_t)(m0 + row) * K + ks;
    xf1 = xf0 + (size_t)16 * K;
  }

  f32x4 acc[2][8];
  f32x4 zero = {0.f, 0.f, 0.f, 0.f};
#pragma unroll
  for (int i = 0; i < 2; ++i)
#pragma unroll
    for (int j = 0; j < 8; ++j) acc[i][j] = zero;

  for (int kc = 0; kc < kch; ++kc) {
    half8 a0, a1;
    if (tk.xh) {                            // fp16 input, direct 16B fragments
      a0 = *(const half8*)(xh0 + (kc << 5));
      a1 = *(const half8*)(xh1 + (kc << 5));
    } else if (K == D) {                    // fp32 dense K=128, 16B-aligned
      float4 p0 = *(const float4*)(xf0 + (kc << 5));
      float4 p1 = *(const float4*)(xf0 + (kc << 5) + 4);
      float4 q0 = *(const float4*)(xf1 + (kc << 5));
      float4 q1 = *(const float4*)(xf1 + (kc << 5) + 4);
      a0[0] = (_Float16)p0.x; a0[1] = (_Float16)p0.y;
      a0[2] = (_Float16)p0.z; a0[3] = (_Float16)p0.w;
      a0[4] = (_Float16)p1.x; a0[5] = (_Float16)p1.y;
      a0[6] = (_Float16)p1.z; a0[7] = (_Float16)p1.w;
      a1[0] = (_Float16)q0.x; a1[1] = (_Float16)q0.y;
      a1[2] = (_Float16)q0.z; a1[3] = (_Float16)q0.w;
      a1[4] = (_Float16)q1.x; a1[5] = (_Float16)q1.y;
      a1[6] = (_Float16)q1.z; a1[7] = (_Float16)q1.w;
    } else {                                // K=74: guarded scalar, zero-padded
#pragma unroll
      for (int e = 0; e < 8; ++e) {
        int k = (kc << 5) + ks + e;
        a0[e] = (k < K) ? (_Float16)xf0[(kc << 5) + e] : (_Float16)0.f;
        a1[e] = (k < K) ? (_Float16)xf1[(kc << 5) + e] : (_Float16)0.f;
      }
    }
#pragma unroll
    for (int nt = 0; nt < 8; ++nt) {
      half8 b = *(const half8*)&Bs[(size_t)((((kc << 3) + nt) << 6) + l) << 3];
      acc[0][nt] = __builtin_amdgcn_mfma_f32_16x16x32_f16(a0, b, acc[0][nt], 0, 0, 0);
      acc[1][nt] = __builtin_amdgcn_mfma_f32_16x16x32_f16(a1, b, acc[1][nt], 0, 0, 0);
    }
  }

  // epilogue: C/D layout col=lane&15, row=(lane>>4)*4+reg
  int rr = (l >> 4) << 2;
  int c0 = l & 15;
#pragma unroll
  for (int mt = 0; mt < 2; ++mt) {
    int vb = m0 + (mt << 4) + rr;
    float s0 = tk.ns[vb], s1 = tk.ns[vb + 1];
    float s2 = tk.ns[vb + 2], s3 = tk.ns[vb + 3];
#pragma unroll
    for (int nt = 0; nt < 8; ++nt) {
      __half* hp = tk.h + (size_t)vb * D + (nt << 4) + c0;
      hp[0]     = __float2half_rn(acc[mt][nt][0] * s0);
      hp[D]     = __float2half_rn(acc[mt][nt][1] * s1);
      hp[2 * D] = __float2half_rn(acc[mt][nt][2] * s2);
      hp[3 * D] = __float2half_rn(acc[mt][nt][3] * s3);
    }
  }
}

// ---- aggregation: wave-per-node (grid-stride), 16 lanes x 8 feats (16B),
//      4 rows/instr, 32 edges per window (8 gathers in flight per lane).
//      Optional perm[] permutes the OUTPUT row (graph-sorted m2 for seg_mean).
__global__ __launch_bounds__(256) void k_aggregate(AggP P) {
  int wid = threadIdx.x >> 6;
  int lane = threadIdx.x & 63;
  int f0 = (lane & 15) * 8;
  int rsel = lane >> 4;
  int nw = (int)gridDim.x * 4;

  for (int gv = blockIdx.x * 4 + wid; gv < P.ntot; gv += nw) {
    ATask tk;
    int v;
    if (gv < P.np) { tk = P.t[0]; v = gv; }
    else           { tk = P.t[1]; v = gv - P.np; }
    int beg = tk.rowptr[v], end = tk.rowptr[v + 1];
    const __half* h = tk.h;
    const int* col = tk.col;

    float acc[8];
#pragma unroll
    for (int k = 0; k < 8; ++k) acc[k] = 0.f;

    for (int j = beg; j < end; j += 32) {
      int cc[8];
#pragma unroll
      for (int q = 0; q < 8; ++q) {
        int jj = j + 4 * q + rsel;
        cc[q] = (jj < end) ? col[jj] : -1;
      }
#pragma unroll
      for (int q = 0; q < 8; ++q) {
        if (cc[q] >= 0) {
          uint4 r = *(const uint4*)&h[(size_t)cc[q] * D + f0];
          const __half2* p = (const __half2*)&r;
#pragma unroll
          for (int k = 0; k < 4; ++k) {
            float2 f = __half22float2(p[k]);
            acc[2 * k] += f.x; acc[2 * k + 1] += f.y;
          }
        }
      }
    }

#pragma unroll
    for (int k = 0; k < 8; ++k) {
      acc[k] += __shfl_down(acc[k], 32, 64);
      acc[k] += __shfl_down(acc[k], 16, 64);
    }

    if (rsel == 0) {
      float s = tk.nd[v];
      float4 b0 = *(const float4*)&tk.b[f0];
      float4 b1 = *(const float4*)&tk.b[f0 + 4];
      float r[8];
      r[0] = fmaxf(fmaf(acc[0], s, b0.x), 0.f);
      r[1] = fmaxf(fmaf(acc[1], s, b0.y), 0.f);
      r[2] = fmaxf(fmaf(acc[2], s, b0.z), 0.f);
      r[3] = fmaxf(fmaf(acc[3], s, b0.w), 0.f);
      r[4] = fmaxf(fmaf(acc[4], s, b1.x), 0.f);
      r[5] = fmaxf(fmaf(acc[5], s, b1.y), 0.f);
      r[6] = fmaxf(fmaf(acc[6], s, b1.z), 0.f);
      r[7] = fmaxf(fmaf(acc[7], s, b1.w), 0.f);
      int ov = tk.perm ? tk.perm[v] : v;
      if (tk.halfOut) {
        union { __half2 h2[4]; uint4 u; } pk;
#pragma unroll
        for (int k = 0; k < 4; ++k) {
          pk.h2[k].x = __float2half_rn(r[2 * k]);
          pk.h2[k].y = __float2half_rn(r[2 * k + 1]);
        }
        *(uint4*)&((__half*)tk.out)[(size_t)ov * D + f0] = pk.u;
      } else {
        float4 o0 = {r[0], r[1], r[2], r[3]};
        float4 o1 = {r[4], r[5], r[6], r[7]};
        *(float4*)&((float*)tk.out)[(size_t)ov * D + f0] = o0;
        *(float4*)&((float*)tk.out)[(size_t)ov * D + f0 + 4] = o1;
      }
    }
  }
}

__device__ __forceinline__ void acc_half4(float4& a, const __half* p) {
  uint2 r = *(const uint2*)p;
  __half2 q0 = *(__half2*)&r.x;
  __half2 q1 = *(__half2*)&r.y;
  float2 f0 = __half22float2(q0);
  float2 f1 = __half22float2(q1);
  a.x += f0.x; a.y += f0.y; a.z += f1.x; a.w += f1.y;
}

// segmented mean over graph-sorted rows: graph g owns rows [gbase[g*NBLK],
// next) of x — purely sequential reads (the writer permuted the rows).
__global__ __launch_bounds__(256) void k_seg_mean(M2 P) {
  MTask tk = P.t[blockIdx.y];
  int g = blockIdx.x, t = threadIdx.x;
  int slot = t >> 5;
  int c = (t & 31) * 4;
  int beg = tk.gbase[g * NBLK];
  int end = (g == (int)gridDim.x - 1) ? tk.n : tk.gbase[(g + 1) * NBLK];
  const __half* x = tk.x;

  float4 a0 = make_float4(0.f, 0.f, 0.f, 0.f);
  float4 a1 = make_float4(0.f, 0.f, 0.f, 0.f);
  int j = beg + slot;
  for (; j + 8 < end; j += 16) {
    acc_half4(a0, x + (size_t)j * D + c);
    acc_half4(a1, x + (size_t)(j + 8) * D + c);
  }
  if (j < end)
    acc_half4(a0, x + (size_t)j * D + c);
  a0.x += a1.x; a0.y += a1.y; a0.z += a1.z; a0.w += a1.w;

  a0.x += __shfl_down(a0.x, 32, 64);
  a0.y += __shfl_down(a0.y, 32, 64);
  a0.z += __shfl_down(a0.z, 32, 64);
  a0.w += __shfl_down(a0.w, 32, 64);

  __shared__ float sred[4][32 * 4];
  int wid = t >> 6, lane = t & 63;
  if (lane < 32) *(float4*)&sred[wid][lane * 4] = a0;
  __syncthreads();
  if (t < 32) {
    float4 s0 = *(const float4*)&sred[0][t * 4];
    float4 s1 = *(const float4*)&sred[1][t * 4];
    float4 s2 = *(const float4*)&sred[2][t * 4];
    float4 s3 = *(const float4*)&sred[3][t * 4];
    float inv = 1.f / fmaxf((float)(end - beg), 1.f);
    float4 r;
    r.x = (s0.x + s1.x + s2.x + s3.x) * inv;
    r.y = (s0.y + s1.y + s2.y + s3.y) * inv;
    r.z = (s0.z + s1.z + s2.z + s3.z) * inv;
    r.w = (s0.w + s1.w + s2.w + s3.w) * inv;
    *(float4*)&tk.out[(size_t)g * D + c] = r;
  }
}

__global__ void k_mlp(const float* __restrict__ cg, const float* __restrict__ pg,
                      const float* __restrict__ Wf1, const float* __restrict__ bf1,
                      const float* __restrict__ Wf2, const float* __restrict__ bf2,
                      float* __restrict__ out) {
  __shared__ float xs[256];
  __shared__ float red[128];
  int b = blockIdx.x, t = threadIdx.x;
  xs[t] = cg[b * D + t];
  xs[128 + t] = pg[b * D + t];
  __syncthreads();
  float acc = bf1[t];
  for (int k = 0; k < 256; ++k) acc = fmaf(xs[k], Wf1[k * D + t], acc);
  float hv = fmaxf(acc, 0.f);
  red[t] = hv * Wf2[t];
  for (int d = 64; d > 0; d >>= 1) {
    __syncthreads();
    if (t < d) red[t] += red[t + d];
  }
  if (t == 0) out[b] = red[0] + bf2[0];
}

// ---------------- launch ------------------------------------------------------

extern "C" void kernel_launch(void* const* d_in, const int* in_sizes, int n_in,
                              void* d_out, int out_size, void* d_ws, size_t ws_size,
                              hipStream_t stream) {
  const float* compound_feat = (const float*)d_in[0];
  const float* protein_feat  = (const float*)d_in[1];
  const int* c_src = (const int*)d_in[2];
  const int* c_dst = (const int*)d_in[3];
  const int* p_src = (const int*)d_in[4];
  const int* p_dst = (const int*)d_in[5];
  const int* c_gid = (const int*)d_in[6];
  const int* p_gid = (const int*)d_in[7];
  const float* Wc1 = (const float*)d_in[8];  const float* bc1 = (const float*)d_in[9];
  const float* Wc2 = (const float*)d_in[10]; const float* bc2 = (const float*)d_in[11];
  const float* Wp1 = (const float*)d_in[12]; const float* bp1 = (const float*)d_in[13];
  const float* Wp2 = (const float*)d_in[14]; const float* bp2 = (const float*)d_in[15];
  const float* Wf1 = (const float*)d_in[16]; const float* bf1 = (const float*)d_in[17];
  const float* Wf2 = (const float*)d_in[18]; const float* bf2 = (const float*)d_in[19];
  float* out = (float*)d_out;

  const int EC = in_sizes[2], EP = in_sizes[4];
  const int NC = in_sizes[6], NP = in_sizes[7];
  const int B  = out_size;
  const int KC = in_sizes[0] / NC;                 // 74
  const int cshift = __builtin_ctz(NC / 256), cfine = NC / 256;
  const int pshift = __builtin_ctz(NP / 256), pfine = NP / 256;
  const int HN = 256 * NBLK;

  char* ws = (char*)d_ws;
  size_t off = 0;
  auto alloc = [&](size_t bytes) -> void* {
    void* p = ws + off;
    off += (bytes + 255) & ~(size_t)255;
    return p;
  };

  int* H0 = (int*)alloc((size_t)HN * 4);
  int* H1 = (int*)alloc((size_t)HN * 4);
  int* H2 = (int*)alloc((size_t)HN * 4);
  int* H3 = (int*)alloc((size_t)HN * 4);
  int* H4 = (int*)alloc((size_t)HN * 4);
  int* H5 = (int*)alloc((size_t)HN * 4);
  int* partH = (int*)alloc((size_t)6 * 32 * 4);
  int* partD = (int*)alloc((size_t)2 * 32 * 4);
  int* tmps_c = (int*)alloc((size_t)EC * 4);
  int* tmpd_c = (int*)alloc((size_t)EC * 4);
  int* tmpv_c = (int*)alloc((size_t)EC * 4);
  int* tmps_p = (int*)alloc((size_t)EP * 4);
  int* tmpd_p = (int*)alloc((size_t)EP * 4);
  int* tmpv_p = (int*)alloc((size_t)EP * 4);
  int* c_outdeg = (int*)alloc((size_t)NC * 4);
  int* c_indeg  = (int*)alloc((size_t)NC * 4);
  int* p_outdeg = (int*)alloc((size_t)NP * 4);
  int* p_indeg  = (int*)alloc((size_t)NP * 4);
  float* c_ns = (float*)alloc((size_t)NC * 4);
  float* c_nd = (float*)alloc((size_t)NC * 4);
  float* p_ns = (float*)alloc((size_t)NP * 4);
  float* p_nd = (float*)alloc((size_t)NP * 4);
  int* c_rowptr = (int*)alloc((size_t)(NC + 1) * 4);
  int* p_rowptr = (int*)alloc((size_t)(NP + 1) * 4);
  int* c_col   = (int*)alloc((size_t)EC * 4);
  int* p_col   = (int*)alloc((size_t)EP * 4);
  int* c_perm = (int*)alloc((size_t)NC * 4);
  int* p_perm = (int*)alloc((size_t)NP * 4);
  __half* c_h  = (__half*)alloc((size_t)NC * D * 2);
  __half* c_m1 = (__half*)alloc((size_t)NC * D * 2);
  __half* c_m2 = (__half*)alloc((size_t)NC * D * 2);
  __half* p_h  = (__half*)alloc((size_t)NP * D * 2);
  __half* p_m1 = (__half*)alloc((size_t)NP * D * 2);
  __half* p_m2 = (__half*)alloc((size_t)NP * D * 2);
  float* cg = (float*)alloc((size_t)B * D * 4);
  float* pg = (float*)alloc((size_t)B * D * 4);
  _Float16* wp_p1 = (_Float16*)alloc((size_t)32 * 1024);
  _Float16* wp_c1 = (_Float16*)alloc((size_t)32 * 1024);
  _Float16* wp_p2 = (_Float16*)alloc((size_t)32 * 1024);
  _Float16* wp_c2 = (_Float16*)alloc((size_t)32 * 1024);
  (void)ws_size; (void)n_in;

  // 0) pack the four W matrices into fp16 MFMA fragment order (independent)
  {
    W4 PW = {{{Wp1, wp_p1, D}, {Wc1, wp_c1, KC}, {Wp2, wp_p2, D}, {Wc2, wp_c2, D}}};
    k_wpack<<<dim3(32, 4), 256, 0, stream>>>(PW);
  }
  // 1) all six 256-bin histograms
  {
    H6 P = {{{c_src, EC, cshift, H0}, {c_dst, EC, cshift, H1}, {c_gid, NC, 0, H2},
             {p_src, EP, pshift, H3}, {p_dst, EP, pshift, H4}, {p_gid, NP, 0, H5}}};
    k_hist_all<<<dim3(NBLK, 6), 256, 0, stream>>>(P);
  }
  // 2) scan the six H arrays in place
  {
    SP6 Pp = {{{H0, HN, partH + 0}, {H1, HN, partH + 32}, {H2, HN, partH + 64},
               {H3, HN, partH + 96}, {H4, HN, partH + 128}, {H5, HN, partH + 160}}};
    k_scan_part_all<<<dim3(16, 6), 256, 0, stream>>>(Pp);
    SD6 Pd = {{{H0, HN, partH + 0, H0, nullptr}, {H1, HN, partH + 32, H1, nullptr},
               {H2, HN, partH + 64, H2, nullptr}, {H3, HN, partH + 96, H3, nullptr},
               {H4, HN, partH + 128, H4, nullptr}, {H5, HN, partH + 160, H5, nullptr}}};
    k_scan_down_all<<<dim3(16, 6), 256, 0, stream>>>(Pd);
  }
  // 3) all level-1 scatters (edge sorts + gid inverse-permutations)
  {
    Sc4 P = {{{c_src, c_dst, EC, cshift, H0, H1, tmps_c, tmpd_c, tmpv_c, 0},
              {p_src, p_dst, EP, pshift, H3, H4, tmps_p, tmpd_p, tmpv_p, 0},
              {c_gid, nullptr, NC, 0, H2, nullptr, c_perm, nullptr, nullptr, 1},
              {p_gid, nullptr, NP, 0, H5, nullptr, p_perm, nullptr, nullptr, 1}}};
    k_scatter_all<<<dim3(NBLK, 4), 256, 0, stream>>>(P);
  }
  // 4) level-2 counts -> degrees
  {
    C4 P = {{{tmps_c, H0, EC, cfine, c_outdeg}, {tmpd_c, H1, EC, cfine, c_indeg},
             {tmps_p, H3, EP, pfine, p_outdeg}, {tmpd_p, H4, EP, pfine, p_indeg}}};
    k_l2count_all<<<dim3(NBLK, 4), 256, 0, stream>>>(P);
  }
  // 5) scan indegrees -> rowptr
  {
    SP6 Pp; Pp.t[0] = {c_indeg, NC, partD + 0}; Pp.t[1] = {p_indeg, NP, partD + 32};
    Pp.t[2] = Pp.t[3] = Pp.t[4] = Pp.t[5] = SPTask{c_indeg, 0, partD + 0};
    k_scan_part_all<<<dim3(32, 2), 256, 0, stream>>>(Pp);
    SD6 Pd; Pd.t[0] = {c_indeg, NC, partD + 0, c_rowptr, c_rowptr + NC};
    Pd.t[1] = {p_indeg, NP, partD + 32, p_rowptr, p_rowptr + NP};
    Pd.t[2] = Pd.t[3] = Pd.t[4] = Pd.t[5] = Pd.t[0];
    k_scan_down_all<<<dim3(32, 2), 256, 0, stream>>>(Pd);
  }
  // 6) norms
  {
    N2 P = {{{c_outdeg, c_indeg, c_ns, c_nd, NC}, {p_outdeg, p_indeg, p_ns, p_nd, NP}}};
    k_norms_all<<<dim3((NP + 255) / 256, 2), 256, 0, stream>>>(P);
  }
  // 7) level-2 scatter -> CSR col
  {
    L2T P = {{{tmpd_c, tmpv_c, H1, EC, c_rowptr, cshift, cfine, c_col},
              {tmpd_p, tmpv_p, H4, EP, p_rowptr, pshift, pfine, p_col}}};
    k_l2scatter_all<<<dim3(NBLK, 2), 256, 0, stream>>>(P);
  }

  // ---- towers (flattened grids: protein first) ----
  const int gnb = NP / 128 + NC / 128;
  const int ntot = NP + NC;
  const int anb = min((ntot + 3) / 4, 8192);   // grid-stride persistent waves
  {
    GemP P = {{{protein_feat, p_ns, wp_p1, p_h, D, 0},
               {compound_feat, c_ns, wp_c1, c_h, KC, 0}}, NP / 128};
    k_nl_gemm<<<gnb, 256, 0, stream>>>(P);
  }
  {
    AggP P = {{{p_h, p_rowptr, p_col, p_nd, bp1, nullptr, p_m1, 1},
               {c_h, c_rowptr, c_col, c_nd, bc1, nullptr, c_m1, 1}}, NP, ntot};
    k_aggregate<<<anb, 256, 0, stream>>>(P);
  }
  {
    GemP P = {{{p_m1, p_ns, wp_p2, p_h, D, 1}, {c_m1, c_ns, wp_c2, c_h, D, 1}}, NP / 128};
    k_nl_gemm<<<gnb, 256, 0, stream>>>(P);
  }
  {
    // layer-2 aggregate writes m2 rows permuted into graph-sorted order
    AggP P = {{{p_h, p_rowptr, p_col, p_nd, bp2, p_perm, p_m2, 1},
               {c_h, c_rowptr, c_col, c_nd, bc2, c_perm, c_m2, 1}}, NP, ntot};
    k_aggregate<<<anb, 256, 0, stream>>>(P);
  }
  {
    M2 P = {{{c_m2, H2, NC, cg}, {p_m2, H5, NP, pg}}};
    k_seg_mean<<<dim3(B, 2), 256, 0, stream>>>(P);
  }

  k_mlp<<<B, D, 0, stream>>>(cg, pg, Wf1, bf1, Wf2, bf2, out);
}

// Round 6
// 502.402 us; speedup vs baseline: 1.0549x; 1.0325x over previous
//
#include <hip/hip_runtime.h>
#include <hip/hip_fp16.h>

#define D 128
#define SCH 4096    // elements per scan block
#define NBLK 256    // blocks per level-1 distribution

typedef _Float16 half8 __attribute__((ext_vector_type(8)));
typedef float f32x4 __attribute__((ext_vector_type(4)));

// ---------------- task structs (passed by value) -----------------------------
struct HTask { const int* keys; int n; int shift; int* H; };
struct H6 { HTask t[6]; };

struct SPTask { const int* in; int n; int* part; };
struct SP6 { SPTask t[6]; };

struct SDTask { const int* in; int n; const int* part; int* out; int* total; };
struct SD6 { SDTask t[6]; };

struct ScTask { const int* k1; const int* k2; int n; int shift; int mask;
                const int* base1; const int* base2;
                unsigned short* o1h; int* o1i; unsigned int* o2; int mode; };
struct Sc4 { ScTask t[4]; };

struct FS { const unsigned short* lows; const int* base; int n; int fine; float* ns; };
struct FD { const unsigned int* pk; const int* base; int n; int fine;
            int* rowptr; int* col; float* nd; int nnodes; };
struct FZ { FS s[2]; FD d[2]; };

struct WPk { const float* W; _Float16* out; int K; };
struct W4 { WPk t[4]; };

struct GTask { const void* x; const float* ns; const _Float16* Wp; __half* h;
               int K; int xh; };
struct GemP { GTask t[2]; int nb0; };

struct ATask { const __half* h; const int* rowptr; const int* col;
               const float* nd; const float* b; const int* perm;
               void* out; int halfOut; };
struct AggP { ATask t[2]; int np; int ntot; };

struct HeadP { const __half* cx; const int* cbase; int cn;
               const __half* px; const int* pbase; int pn;
               const float* Wf1; const float* bf1; const float* Wf2; const float* bf2;
               float* out; };

// ---------------- fused preprocessing ----------------------------------------

__global__ __launch_bounds__(256) void k_hist_all(H6 P) {
  HTask tk = P.t[blockIdx.y];
  __shared__ int bins[256];
  int blk = blockIdx.x, t = threadIdx.x;
  bins[t] = 0;
  __syncthreads();
  int per = (tk.n + NBLK - 1) / NBLK;
  int beg = blk * per, end = min(beg + per, tk.n);
  for (int i = beg + t; i < end; i += 256)
    atomicAdd(&bins[tk.keys[i] >> tk.shift], 1);
  __syncthreads();
  tk.H[t * NBLK + blk] = bins[t];
}

__global__ __launch_bounds__(256) void k_scan_part_all(SP6 P) {
  SPTask tk = P.t[blockIdx.y];
  int b = blockIdx.x, t = threadIdx.x;
  int base = b * SCH;
  int s = 0;
  for (int i = t; i < SCH; i += 256) {
    int idx = base + i;
    if (idx < tk.n) s += tk.in[idx];
  }
  __shared__ int red[256];
  red[t] = s;
  __syncthreads();
  for (int d = 128; d > 0; d >>= 1) {
    if (t < d) red[t] += red[t + d];
    __syncthreads();
  }
  if (t == 0) tk.part[b] = red[0];
}

__global__ __launch_bounds__(256) void k_scan_down_all(SD6 P) {
  SDTask tk = P.t[blockIdx.y];
  int b = blockIdx.x, t = threadIdx.x;
  int lane = t & 63, wid = t >> 6;
  __shared__ int wsum[4];
  if (b == 0 && t == 0 && tk.total) {
    int s = 0;
    for (int w = 0; w < (int)gridDim.x; ++w) s += tk.part[w];
    *tk.total = s;
  }
  int offset = 0;
  for (int w = 0; w < b; ++w) offset += tk.part[w];
  int base = b * SCH;
  if (base >= tk.n) return;
  int idx0 = base + t * 16;
  int v[16];
  int s = 0;
#pragma unroll
  for (int i = 0; i < 16; ++i) {
    int idx = idx0 + i;
    v[i] = (idx < tk.n) ? tk.in[idx] : 0;
    s += v[i];
  }
  int inc = s;
  for (int d = 1; d < 64; d <<= 1) {
    int u = __shfl_up(inc, d, 64);
    if (lane >= d) inc += u;
  }
  if (lane == 63) wsum[wid] = inc;
  __syncthreads();
  int woff = 0;
  for (int w = 0; w < wid; ++w) woff += wsum[w];
  int ex = offset + woff + inc - s;
#pragma unroll
  for (int i = 0; i < 16; ++i) {
    int idx = idx0 + i;
    if (idx < tk.n) tk.out[idx] = ex;
    ex += v[i];
  }
}

// level-1 scatter.  mode 0: edge sort — writes low-bits of src (u16) into
// src-sorted order and (dst_low<<17 | src) packed u32 into dst-sorted order.
// mode 1: gid inverse permutation perm[i] = graph-sorted position of node i.
__global__ __launch_bounds__(256) void k_scatter_all(Sc4 P) {
  ScTask tk = P.t[blockIdx.y];
  __shared__ int curA[256], curB[256];
  int blk = blockIdx.x, t = threadIdx.x;
  curA[t] = tk.base1[t * NBLK + blk];
  if (tk.mode == 0) curB[t] = tk.base2[t * NBLK + blk];
  __syncthreads();
  int per = (tk.n + NBLK - 1) / NBLK;
  int beg = blk * per, end = min(beg + per, tk.n);
  if (tk.mode == 0) {
    for (int i = beg + t; i < end; i += 256) {
      int s = tk.k1[i], d = tk.k2[i];
      int pa = atomicAdd(&curA[s >> tk.shift], 1);
      tk.o1h[pa] = (unsigned short)(s & tk.mask);
      int pb = atomicAdd(&curB[d >> tk.shift], 1);
      tk.o2[pb] = ((unsigned int)(d & tk.mask) << 17) | (unsigned int)s;
    }
  } else {
    for (int i = beg + t; i < end; i += 256) {
      int pa = atomicAdd(&curA[tk.k1[i] >> tk.shift], 1);
      tk.o1i[i] = pa;
    }
  }
}

// fused level-2: per level-1 bin, count -> block-local exclusive scan ->
// rowptr/nd/ns -> CSR col scatter.  No global scan needed: bin b's edges are
// contiguous in the level-1 output and bin b covers nodes [b*fine,(b+1)*fine).
__global__ __launch_bounds__(256) void k_l2fused(FZ P) {
  __shared__ int bins[512];
  __shared__ int pos[512];
  __shared__ int wsum[4];
  int b = blockIdx.x, t = threadIdx.x, ty = blockIdx.y;
  if (ty < 2) {
    FS tk = P.s[ty];
    for (int f = t; f < tk.fine; f += 256) bins[f] = 0;
    __syncthreads();
    int beg = tk.base[b * NBLK];
    int end = (b == NBLK - 1) ? tk.n : tk.base[(b + 1) * NBLK];
    for (int i = beg + t; i < end; i += 256)
      atomicAdd(&bins[tk.lows[i]], 1);
    __syncthreads();
    int v0 = b * tk.fine;
    for (int f = t; f < tk.fine; f += 256)
      tk.ns[v0 + f] = rsqrtf(fmaxf((float)bins[f], 1.f));
  } else {
    FD tk = P.d[ty - 2];
    for (int f = t; f < tk.fine; f += 256) bins[f] = 0;
    __syncthreads();
    int beg = tk.base[b * NBLK];
    int end = (b == NBLK - 1) ? tk.n : tk.base[(b + 1) * NBLK];
    for (int i = beg + t; i < end; i += 256)
      atomicAdd(&bins[tk.pk[i] >> 17], 1);
    __syncthreads();
    // block-local exclusive scan of bins -> pos, seeded with segment base
    int lane = t & 63, wid = t >> 6;
    int c = (tk.fine + 255) >> 8;          // bins per thread: 1 or 2
    int i0 = t * c;
    int vc[2] = {0, 0};
    int s = 0;
#pragma unroll
    for (int q = 0; q < 2; ++q) {
      if (q < c && i0 + q < tk.fine) { vc[q] = bins[i0 + q]; s += vc[q]; }
    }
    int inc = s;
    for (int dd = 1; dd < 64; dd <<= 1) {
      int u = __shfl_up(inc, dd, 64);
      if (lane >= dd) inc += u;
    }
    if (lane == 63) wsum[wid] = inc;
    __syncthreads();
    int woff = 0;
    for (int w = 0; w < wid; ++w) woff += wsum[w];
    int ex = beg + woff + inc - s;
#pragma unroll
    for (int q = 0; q < 2; ++q) {
      if (q < c && i0 + q < tk.fine) { pos[i0 + q] = ex; ex += vc[q]; }
    }
    __syncthreads();
    // emit rowptr + nd (before pos is consumed as a cursor)
    int v0 = b * tk.fine;
    for (int f = t; f < tk.fine; f += 256) {
      tk.rowptr[v0 + f] = pos[f];
      tk.nd[v0 + f] = rsqrtf(fmaxf((float)bins[f], 1.f));
    }
    if (b == NBLK - 1 && t == 0) tk.rowptr[tk.nnodes] = tk.n;
    __syncthreads();
    // pass 2: scatter CSR col
    for (int i = beg + t; i < end; i += 256) {
      unsigned int pk = tk.pk[i];
      int p = atomicAdd(&pos[pk >> 17], 1);
      tk.col[p] = (int)(pk & 0x1FFFFu);
    }
  }
}

// ---------------- towers ------------------------------------------------------

// Pack W (K x 128, fp32) into MFMA-B-fragment order, fp16:
//   out[((kc*8+nt)*64 + lane)*8 + e] = W[kc*32 + (lane>>4)*8 + e][nt*16 + (lane&15)]
__global__ __launch_bounds__(256) void k_wpack(W4 P) {
  WPk tk = P.t[blockIdx.y];
  int f = blockIdx.x;                       // fragment id 0..31
  int kch = (tk.K + 31) >> 5;
  if (f >= (kch << 3)) return;
  int kc = f >> 3, nt = f & 7;
  int t = threadIdx.x;
  int l = t & 63, e0 = (t >> 6) << 1;       // each thread handles 2 e-slots
  int col = (nt << 4) + (l & 15);
  int kb = (kc << 5) + ((l >> 4) << 3);
#pragma unroll
  for (int e = e0; e < e0 + 2; ++e) {
    int k = kb + e;
    float v = (k < tk.K) ? tk.W[(size_t)k * D + col] : 0.f;
    tk.out[(((size_t)f * 64 + l) << 3) + e] = (_Float16)v;
  }
}

// h[v,:] = fp16( ns[v] * (x[v,:] @ W) ) via mfma_f32_16x16x32_f16.
// 128 nodes x 128 feats per 256-thread block (4 waves). Wave w owns rows
// [w*32, w*32+32): 2 M-tiles x 8 N-tiles of 16x16, K swept in 32-chunks.
__global__ __launch_bounds__(256) void k_nl_gemm(GemP P) {
  __shared__ __align__(16) _Float16 Bs[32 * 64 * 8];   // 32 KB
  int bx = blockIdx.x;
  GTask tk;
  int v0;
  if (bx < P.nb0) { tk = P.t[0]; v0 = bx * 128; }
  else            { tk = P.t[1]; v0 = (bx - P.nb0) * 128; }
  const int K = tk.K;
  const int kch = (K + 31) >> 5;            // 4 (K=128) or 3 (K=74)
  int t = threadIdx.x, w = t >> 6, l = t & 63;

  // stage packed W into LDS (linear copy)
  {
    const uint4* src = (const uint4*)tk.Wp;
    uint4* dst = (uint4*)Bs;
    int n16 = kch << 9;                     // kch*8 frags * 64 lanes
    for (int i = t; i < n16; i += 256) dst[i] = src[i];
  }
  __syncthreads();

  int row = l & 15;
  int ks = (l >> 4) << 3;                   // k offset within 32-chunk
  int m0 = v0 + (w << 5);
  const float* xf0 = nullptr; const float* xf1 = nullptr;
  const _Float16* xh0 = nullptr; const _Float16* xh1 = nullptr;
  if (tk.xh) {
    xh0 = (const _Float16*)tk.x + (size_t)(m0 + row) * D + ks;
    xh1 = xh0 + (size_t)16 * D;
  } else {
    xf0 = (const float*)tk.x + (size_t)(m0 + row) * K + ks;
    xf1 = xf0 + (size_t)16 * K;
  }

  f32x4 acc[2][8];
  f32x4 zero = {0.f, 0.f, 0.f, 0.f};
#pragma unroll
  for (int i = 0; i < 2; ++i)
#pragma unroll
    for (int j = 0; j < 8; ++j) acc[i][j] = zero;

  for (int kc = 0; kc < kch; ++kc) {
    half8 a0, a1;
    if (tk.xh) {                            // fp16 input, direct 16B fragments
      a0 = *(const half8*)(xh0 + (kc << 5));
      a1 = *(const half8*)(xh1 + (kc << 5));
    } else if (K == D) {                    // fp32 dense K=128, 16B-aligned
      float4 p0 = *(const float4*)(xf0 + (kc << 5));
      float4 p1 = *(const float4*)(xf0 + (kc << 5) + 4);
      float4 q0 = *(const float4*)(xf1 + (kc << 5));
      float4 q1 = *(const float4*)(xf1 + (kc << 5) + 4);
      a0[0] = (_Float16)p0.x; a0[1] = (_Float16)p0.y;
      a0[2] = (_Float16)p0.z; a0[3] = (_Float16)p0.w;
      a0[4] = (_Float16)p1.x; a0[5] = (_Float16)p1.y;
      a0[6] = (_Float16)p1.z; a0[7] = (_Float16)p1.w;
      a1[0] = (_Float16)q0.x; a1[1] = (_Float16)q0.y;
      a1[2] = (_Float16)q0.z; a1[3] = (_Float16)q0.w;
      a1[4] = (_Float16)q1.x; a1[5] = (_Float16)q1.y;
      a1[6] = (_Float16)q1.z; a1[7] = (_Float16)q1.w;
    } else {                                // K=74: guarded scalar, zero-padded
#pragma unroll
      for (int e = 0; e < 8; ++e) {
        int k = (kc << 5) + ks + e;
        a0[e] = (k < K) ? (_Float16)xf0[(kc << 5) + e] : (_Float16)0.f;
        a1[e] = (k < K) ? (_Float16)xf1[(kc << 5) + e] : (_Float16)0.f;
      }
    }
#pragma unroll
    for (int nt = 0; nt < 8; ++nt) {
      half8 b = *(const half8*)&Bs[(size_t)((((kc << 3) + nt) << 6) + l) << 3];
      acc[0][nt] = __builtin_amdgcn_mfma_f32_16x16x32_f16(a0, b, acc[0][nt], 0, 0, 0);
      acc[1][nt] = __builtin_amdgcn_mfma_f32_16x16x32_f16(a1, b, acc[1][nt], 0, 0, 0);
    }
  }

  // epilogue: C/D layout col=lane&15, row=(lane>>4)*4+reg
  int rr = (l >> 4) << 2;
  int c0 = l & 15;
#pragma unroll
  for (int mt = 0; mt < 2; ++mt) {
    int vb = m0 + (mt << 4) + rr;
    float s0 = tk.ns[vb], s1 = tk.ns[vb + 1];
    float s2 = tk.ns[vb + 2], s3 = tk.ns[vb + 3];
#pragma unroll
    for (int nt = 0; nt < 8; ++nt) {
      __half* hp = tk.h + (size_t)vb * D + (nt << 4) + c0;
      hp[0]     = __float2half_rn(acc[mt][nt][0] * s0);
      hp[D]     = __float2half_rn(acc[mt][nt][1] * s1);
      hp[2 * D] = __float2half_rn(acc[mt][nt][2] * s2);
      hp[3 * D] = __float2half_rn(acc[mt][nt][3] * s3);
    }
  }
}

// ---- aggregation: wave-per-node (grid-stride), 16 lanes x 8 feats (16B),
//      4 rows/instr, 32 edges per window (8 gathers in flight per lane).
//      Optional perm[] permutes the OUTPUT row (graph-sorted m2 for k_head).
__global__ __launch_bounds__(256) void k_aggregate(AggP P) {
  int wid = threadIdx.x >> 6;
  int lane = threadIdx.x & 63;
  int f0 = (lane & 15) * 8;
  int rsel = lane >> 4;
  int nw = (int)gridDim.x * 4;

  for (int gv = blockIdx.x * 4 + wid; gv < P.ntot; gv += nw) {
    ATask tk;
    int v;
    if (gv < P.np) { tk = P.t[0]; v = gv; }
    else           { tk = P.t[1]; v = gv - P.np; }
    int beg = tk.rowptr[v], end = tk.rowptr[v + 1];
    const __half* h = tk.h;
    const int* col = tk.col;

    float acc[8];
#pragma unroll
    for (int k = 0; k < 8; ++k) acc[k] = 0.f;

    for (int j = beg; j < end; j += 32) {
      int cc[8];
#pragma unroll
      for (int q = 0; q < 8; ++q) {
        int jj = j + 4 * q + rsel;
        cc[q] = (jj < end) ? col[jj] : -1;
      }
#pragma unroll
      for (int q = 0; q < 8; ++q) {
        if (cc[q] >= 0) {
          uint4 r = *(const uint4*)&h[(size_t)cc[q] * D + f0];
          const __half2* p = (const __half2*)&r;
#pragma unroll
          for (int k = 0; k < 4; ++k) {
            float2 f = __half22float2(p[k]);
            acc[2 * k] += f.x; acc[2 * k + 1] += f.y;
          }
        }
      }
    }

#pragma unroll
    for (int k = 0; k < 8; ++k) {
      acc[k] += __shfl_down(acc[k], 32, 64);
      acc[k] += __shfl_down(acc[k], 16, 64);
    }

    if (rsel == 0) {
      float s = tk.nd[v];
      float4 b0 = *(const float4*)&tk.b[f0];
      float4 b1 = *(const float4*)&tk.b[f0 + 4];
      float r[8];
      r[0] = fmaxf(fmaf(acc[0], s, b0.x), 0.f);
      r[1] = fmaxf(fmaf(acc[1], s, b0.y), 0.f);
      r[2] = fmaxf(fmaf(acc[2], s, b0.z), 0.f);
      r[3] = fmaxf(fmaf(acc[3], s, b0.w), 0.f);
      r[4] = fmaxf(fmaf(acc[4], s, b1.x), 0.f);
      r[5] = fmaxf(fmaf(acc[5], s, b1.y), 0.f);
      r[6] = fmaxf(fmaf(acc[6], s, b1.z), 0.f);
      r[7] = fmaxf(fmaf(acc[7], s, b1.w), 0.f);
      int ov = tk.perm ? tk.perm[v] : v;
      if (tk.halfOut) {
        union { __half2 h2[4]; uint4 u; } pk;
#pragma unroll
        for (int k = 0; k < 4; ++k) {
          pk.h2[k].x = __float2half_rn(r[2 * k]);
          pk.h2[k].y = __float2half_rn(r[2 * k + 1]);
        }
        *(uint4*)&((__half*)tk.out)[(size_t)ov * D + f0] = pk.u;
      } else {
        float4 o0 = {r[0], r[1], r[2], r[3]};
        float4 o1 = {r[4], r[5], r[6], r[7]};
        *(float4*)&((float*)tk.out)[(size_t)ov * D + f0] = o0;
        *(float4*)&((float*)tk.out)[(size_t)ov * D + f0 + 4] = o1;
      }
    }
  }
}

__device__ __forceinline__ void acc_half4(float4& a, const __half* p) {
  uint2 r = *(const uint2*)p;
  __half2 q0 = *(__half2*)&r.x;
  __half2 q1 = *(__half2*)&r.y;
  float2 f0 = __half22float2(q0);
  float2 f1 = __half22float2(q1);
  a.x += f0.x; a.y += f0.y; a.z += f1.x; a.w += f1.y;
}

// mean over graph-sorted rows [beg,end) of x -> dst[0..127] (in LDS)
__device__ __forceinline__ void block_mean_128(const __half* x, int beg, int end,
                                               float* dst, float (*sred)[128]) {
  int t = threadIdx.x;
  int slot = t >> 5;
  int c = (t & 31) * 4;
  float4 a0 = make_float4(0.f, 0.f, 0.f, 0.f);
  float4 a1 = make_float4(0.f, 0.f, 0.f, 0.f);
  int j = beg + slot;
  for (; j + 8 < end; j += 16) {
    acc_half4(a0, x + (size_t)j * D + c);
    acc_half4(a1, x + (size_t)(j + 8) * D + c);
  }
  if (j < end)
    acc_half4(a0, x + (size_t)j * D + c);
  a0.x += a1.x; a0.y += a1.y; a0.z += a1.z; a0.w += a1.w;

  a0.x += __shfl_down(a0.x, 32, 64);
  a0.y += __shfl_down(a0.y, 32, 64);
  a0.z += __shfl_down(a0.z, 32, 64);
  a0.w += __shfl_down(a0.w, 32, 64);

  int wid = t >> 6, lane = t & 63;
  if (lane < 32) *(float4*)&sred[wid][lane * 4] = a0;
  __syncthreads();
  if (t < 32) {
    float4 s0 = *(const float4*)&sred[0][t * 4];
    float4 s1 = *(const float4*)&sred[1][t * 4];
    float4 s2 = *(const float4*)&sred[2][t * 4];
    float4 s3 = *(const float4*)&sred[3][t * 4];
    float inv = 1.f / fmaxf((float)(end - beg), 1.f);
    float4 r;
    r.x = (s0.x + s1.x + s2.x + s3.x) * inv;
    r.y = (s0.y + s1.y + s2.y + s3.y) * inv;
    r.z = (s0.z + s1.z + s2.z + s3.z) * inv;
    r.w = (s0.w + s1.w + s2.w + s3.w) * inv;
    *(float4*)&dst[t * 4] = r;
  }
  __syncthreads();
}

// fused readout: per graph, compound mean + protein mean + 2-layer MLP
__global__ __launch_bounds__(256) void k_head(HeadP P) {
  __shared__ float xs[256];
  __shared__ float sred[4][128];
  int g = blockIdx.x, t = threadIdx.x;
  int nb = (int)gridDim.x;

  int cb = P.cbase[g * NBLK];
  int ce = (g == nb - 1) ? P.cn : P.cbase[(g + 1) * NBLK];
  block_mean_128(P.cx, cb, ce, xs, sred);
  int pb = P.pbase[g * NBLK];
  int pe = (g == nb - 1) ? P.pn : P.pbase[(g + 1) * NBLK];
  block_mean_128(P.px, pb, pe, xs + 128, sred);

  // MLP: hidden 128; 256 threads -> each half-k range per hidden unit
  int hu = t & 127, half = t >> 7;
  float acc = 0.f;
  int k0 = half * 128;
  for (int k = k0; k < k0 + 128; ++k)
    acc = fmaf(xs[k], P.Wf1[k * D + hu], acc);
  float* hacc = &sred[2][0];   // 256 floats
  float* red = &sred[0][0];    // 128 floats
  hacc[t] = acc;
  __syncthreads();
  if (t < 128) {
    float hv = fmaxf(hacc[t] + hacc[t + 128] + P.bf1[t], 0.f);
    red[t] = hv * P.Wf2[t];
  }
  for (int d = 64; d > 0; d >>= 1) {
    __syncthreads();
    if (t < d) red[t] += red[t + d];
  }
  if (t == 0) P.out[g] = red[0] + P.bf2[0];
}

// ---------------- launch ------------------------------------------------------

extern "C" void kernel_launch(void* const* d_in, const int* in_sizes, int n_in,
                              void* d_out, int out_size, void* d_ws, size_t ws_size,
                              hipStream_t stream) {
  const float* compound_feat = (const float*)d_in[0];
  const float* protein_feat  = (const float*)d_in[1];
  const int* c_src = (const int*)d_in[2];
  const int* c_dst = (const int*)d_in[3];
  const int* p_src = (const int*)d_in[4];
  const int* p_dst = (const int*)d_in[5];
  const int* c_gid = (const int*)d_in[6];
  const int* p_gid = (const int*)d_in[7];
  const float* Wc1 = (const float*)d_in[8];  const float* bc1 = (const float*)d_in[9];
  const float* Wc2 = (const float*)d_in[10]; const float* bc2 = (const float*)d_in[11];
  const float* Wp1 = (const float*)d_in[12]; const float* bp1 = (const float*)d_in[13];
  const float* Wp2 = (const float*)d_in[14]; const float* bp2 = (const float*)d_in[15];
  const float* Wf1 = (const float*)d_in[16]; const float* bf1 = (const float*)d_in[17];
  const float* Wf2 = (const float*)d_in[18]; const float* bf2 = (const float*)d_in[19];
  float* out = (float*)d_out;

  const int EC = in_sizes[2], EP = in_sizes[4];
  const int NC = in_sizes[6], NP = in_sizes[7];
  const int B  = out_size;
  const int KC = in_sizes[0] / NC;                 // 74
  const int cshift = __builtin_ctz(NC / 256), cfine = NC / 256;
  const int pshift = __builtin_ctz(NP / 256), pfine = NP / 256;
  const int HN = 256 * NBLK;

  char* ws = (char*)d_ws;
  size_t off = 0;
  auto alloc = [&](size_t bytes) -> void* {
    void* p = ws + off;
    off += (bytes + 255) & ~(size_t)255;
    return p;
  };

  int* H0 = (int*)alloc((size_t)HN * 4);
  int* H1 = (int*)alloc((size_t)HN * 4);
  int* H2 = (int*)alloc((size_t)HN * 4);
  int* H3 = (int*)alloc((size_t)HN * 4);
  int* H4 = (int*)alloc((size_t)HN * 4);
  int* H5 = (int*)alloc((size_t)HN * 4);
  int* partH = (int*)alloc((size_t)6 * 32 * 4);
  unsigned short* tmps_c = (unsigned short*)alloc((size_t)EC * 2);
  unsigned short* tmps_p = (unsigned short*)alloc((size_t)EP * 2);
  unsigned int* tmpe_c = (unsigned int*)alloc((size_t)EC * 4);
  unsigned int* tmpe_p = (unsigned int*)alloc((size_t)EP * 4);
  float* c_ns = (float*)alloc((size_t)NC * 4);
  float* c_nd = (float*)alloc((size_t)NC * 4);
  float* p_ns = (float*)alloc((size_t)NP * 4);
  float* p_nd = (float*)alloc((size_t)NP * 4);
  int* c_rowptr = (int*)alloc((size_t)(NC + 1) * 4);
  int* p_rowptr = (int*)alloc((size_t)(NP + 1) * 4);
  int* c_col   = (int*)alloc((size_t)EC * 4);
  int* p_col   = (int*)alloc((size_t)EP * 4);
  int* c_perm = (int*)alloc((size_t)NC * 4);
  int* p_perm = (int*)alloc((size_t)NP * 4);
  __half* c_h  = (__half*)alloc((size_t)NC * D * 2);
  __half* c_m1 = (__half*)alloc((size_t)NC * D * 2);
  __half* c_m2 = (__half*)alloc((size_t)NC * D * 2);
  __half* p_h  = (__half*)alloc((size_t)NP * D * 2);
  __half* p_m1 = (__half*)alloc((size_t)NP * D * 2);
  __half* p_m2 = (__half*)alloc((size_t)NP * D * 2);
  _Float16* wp_p1 = (_Float16*)alloc((size_t)32 * 1024);
  _Float16* wp_c1 = (_Float16*)alloc((size_t)32 * 1024);
  _Float16* wp_p2 = (_Float16*)alloc((size_t)32 * 1024);
  _Float16* wp_c2 = (_Float16*)alloc((size_t)32 * 1024);
  (void)ws_size; (void)n_in;

  // 0) pack the four W matrices into fp16 MFMA fragment order (independent)
  {
    W4 PW = {{{Wp1, wp_p1, D}, {Wc1, wp_c1, KC}, {Wp2, wp_p2, D}, {Wc2, wp_c2, D}}};
    k_wpack<<<dim3(32, 4), 256, 0, stream>>>(PW);
  }
  // 1) all six 256-bin histograms
  {
    H6 P = {{{c_src, EC, cshift, H0}, {c_dst, EC, cshift, H1}, {c_gid, NC, 0, H2},
             {p_src, EP, pshift, H3}, {p_dst, EP, pshift, H4}, {p_gid, NP, 0, H5}}};
    k_hist_all<<<dim3(NBLK, 6), 256, 0, stream>>>(P);
  }
  // 2) scan the six H arrays in place
  {
    SP6 Pp = {{{H0, HN, partH + 0}, {H1, HN, partH + 32}, {H2, HN, partH + 64},
               {H3, HN, partH + 96}, {H4, HN, partH + 128}, {H5, HN, partH + 160}}};
    k_scan_part_all<<<dim3(16, 6), 256, 0, stream>>>(Pp);
    SD6 Pd = {{{H0, HN, partH + 0, H0, nullptr}, {H1, HN, partH + 32, H1, nullptr},
               {H2, HN, partH + 64, H2, nullptr}, {H3, HN, partH + 96, H3, nullptr},
               {H4, HN, partH + 128, H4, nullptr}, {H5, HN, partH + 160, H5, nullptr}}};
    k_scan_down_all<<<dim3(16, 6), 256, 0, stream>>>(Pd);
  }
  // 3) level-1 scatters (packed edge sorts + gid inverse-permutations)
  {
    Sc4 P = {{{c_src, c_dst, EC, cshift, cfine - 1, H0, H1, tmps_c, nullptr, tmpe_c, 0},
              {p_src, p_dst, EP, pshift, pfine - 1, H3, H4, tmps_p, nullptr, tmpe_p, 0},
              {c_gid, nullptr, NC, 0, 0, H2, nullptr, nullptr, c_perm, nullptr, 1},
              {p_gid, nullptr, NP, 0, 0, H5, nullptr, nullptr, p_perm, nullptr, 1}}};
    k_scatter_all<<<dim3(NBLK, 4), 256, 0, stream>>>(P);
  }
  // 4) fused level-2: counts -> ns / (rowptr, nd, col)
  {
    FZ PF = {{{tmps_c, H0, EC, cfine, c_ns}, {tmps_p, H3, EP, pfine, p_ns}},
             {{tmpe_c, H1, EC, cfine, c_rowptr, c_col, c_nd, NC},
              {tmpe_p, H4, EP, pfine, p_rowptr, p_col, p_nd, NP}}};
    k_l2fused<<<dim3(NBLK, 4), 256, 0, stream>>>(PF);
  }

  // ---- towers (flattened grids: protein first) ----
  const int gnb = NP / 128 + NC / 128;
  const int ntot = NP + NC;
  const int anb = min((ntot + 3) / 4, 8192);   // grid-stride persistent waves
  {
    GemP P = {{{protein_feat, p_ns, wp_p1, p_h, D, 0},
               {compound_feat, c_ns, wp_c1, c_h, KC, 0}}, NP / 128};
    k_nl_gemm<<<gnb, 256, 0, stream>>>(P);
  }
  {
    AggP P = {{{p_h, p_rowptr, p_col, p_nd, bp1, nullptr, p_m1, 1},
               {c_h, c_rowptr, c_col, c_nd, bc1, nullptr, c_m1, 1}}, NP, ntot};
    k_aggregate<<<anb, 256, 0, stream>>>(P);
  }
  {
    GemP P = {{{p_m1, p_ns, wp_p2, p_h, D, 1}, {c_m1, c_ns, wp_c2, c_h, D, 1}}, NP / 128};
    k_nl_gemm<<<gnb, 256, 0, stream>>>(P);
  }
  {
    // layer-2 aggregate writes m2 rows permuted into graph-sorted order
    AggP P = {{{p_h, p_rowptr, p_col, p_nd, bp2, p_perm, p_m2, 1},
               {c_h, c_rowptr, c_col, c_nd, bc2, c_perm, c_m2, 1}}, NP, ntot};
    k_aggregate<<<anb, 256, 0, stream>>>(P);
  }
  // 5) fused readout: means + predictor MLP
  {
    HeadP PH = {c_m2, H2, NC, p_m2, H5, NP, Wf1, bf1, Wf2, bf2, out};
    k_head<<<B, 256, 0, stream>>>(PH);
  }
}

// Round 7
// 494.768 us; speedup vs baseline: 1.0712x; 1.0154x over previous
//
#include <hip/hip_runtime.h>
#include <hip/hip_fp16.h>

#define D 128
#define SCH 4096    // elements per scan block
#define NBLK 256    // blocks per level-1 distribution

typedef _Float16 half8 __attribute__((ext_vector_type(8)));
typedef float f32x4 __attribute__((ext_vector_type(4)));

// ---------------- task structs (passed by value) -----------------------------
struct HTask { const int* keys; int n; int shift; int* H; };
struct H6 { HTask t[6]; };

struct SPTask { const int* in; int n; int* part; };
struct SP6 { SPTask t[6]; };

struct SDTask { const int* in; int n; const int* part; int* out; int* total; };
struct SD6 { SDTask t[6]; };

struct ScTask { const int* k1; const int* k2; int n; int shift; int mask;
                const int* base1; const int* base2;
                unsigned short* o1h; int* o1i; unsigned int* o2; int mode; };
struct Sc4 { ScTask t[4]; };

struct FS { const unsigned short* lows; const int* base; int n; int fine; float* ns; };
struct FD { const unsigned int* pk; const int* base; int n; int fine;
            int* rowptr; int* col; float* nd; int nnodes; };
struct FZ { FS s[2]; FD d[2]; };

struct WPk { const float* W; _Float16* out; int K; };
struct W4 { WPk t[4]; };

struct GTask { const void* x; const float* ns; const _Float16* Wp; __half* h;
               int K; int xh; };
struct GemP { GTask t[2]; int nb0; };

struct ATask { const __half* h; const int* rowptr; const int* col;
               const float* nd; const float* b; const int* perm;
               void* out; int halfOut; };
struct AggP { ATask t[2]; int np; int ntot; };

struct HeadP { const __half* cx; const int* cbase; int cn;
               const __half* px; const int* pbase; int pn;
               const float* Wf1; const float* bf1; const float* Wf2; const float* bf2;
               float* out; };

// ---------------- fused preprocessing ----------------------------------------

__global__ __launch_bounds__(256) void k_hist_all(H6 P) {
  HTask tk = P.t[blockIdx.y];
  __shared__ int bins[256];
  int blk = blockIdx.x, t = threadIdx.x;
  bins[t] = 0;
  __syncthreads();
  int per = (tk.n + NBLK - 1) / NBLK;
  int beg = blk * per, end = min(beg + per, tk.n);
  for (int i = beg + t; i < end; i += 256)
    atomicAdd(&bins[tk.keys[i] >> tk.shift], 1);
  __syncthreads();
  tk.H[t * NBLK + blk] = bins[t];
}

__global__ __launch_bounds__(256) void k_scan_part_all(SP6 P) {
  SPTask tk = P.t[blockIdx.y];
  int b = blockIdx.x, t = threadIdx.x;
  int base = b * SCH;
  int s = 0;
  for (int i = t; i < SCH; i += 256) {
    int idx = base + i;
    if (idx < tk.n) s += tk.in[idx];
  }
  __shared__ int red[256];
  red[t] = s;
  __syncthreads();
  for (int d = 128; d > 0; d >>= 1) {
    if (t < d) red[t] += red[t + d];
    __syncthreads();
  }
  if (t == 0) tk.part[b] = red[0];
}

__global__ __launch_bounds__(256) void k_scan_down_all(SD6 P) {
  SDTask tk = P.t[blockIdx.y];
  int b = blockIdx.x, t = threadIdx.x;
  int lane = t & 63, wid = t >> 6;
  __shared__ int wsum[4];
  if (b == 0 && t == 0 && tk.total) {
    int s = 0;
    for (int w = 0; w < (int)gridDim.x; ++w) s += tk.part[w];
    *tk.total = s;
  }
  int offset = 0;
  for (int w = 0; w < b; ++w) offset += tk.part[w];
  int base = b * SCH;
  if (base >= tk.n) return;
  int idx0 = base + t * 16;
  int v[16];
  int s = 0;
#pragma unroll
  for (int i = 0; i < 16; ++i) {
    int idx = idx0 + i;
    v[i] = (idx < tk.n) ? tk.in[idx] : 0;
    s += v[i];
  }
  int inc = s;
  for (int d = 1; d < 64; d <<= 1) {
    int u = __shfl_up(inc, d, 64);
    if (lane >= d) inc += u;
  }
  if (lane == 63) wsum[wid] = inc;
  __syncthreads();
  int woff = 0;
  for (int w = 0; w < wid; ++w) woff += wsum[w];
  int ex = offset + woff + inc - s;
#pragma unroll
  for (int i = 0; i < 16; ++i) {
    int idx = idx0 + i;
    if (idx < tk.n) tk.out[idx] = ex;
    ex += v[i];
  }
}

// level-1 scatter.  mode 0: edge sort — writes low-bits of src (u16) into
// src-sorted order and (dst_low<<17 | src) packed u32 into dst-sorted order.
// mode 1: gid inverse permutation perm[i] = graph-sorted position of node i.
__global__ __launch_bounds__(256) void k_scatter_all(Sc4 P) {
  ScTask tk = P.t[blockIdx.y];
  __shared__ int curA[256], curB[256];
  int blk = blockIdx.x, t = threadIdx.x;
  curA[t] = tk.base1[t * NBLK + blk];
  if (tk.mode == 0) curB[t] = tk.base2[t * NBLK + blk];
  __syncthreads();
  int per = (tk.n + NBLK - 1) / NBLK;
  int beg = blk * per, end = min(beg + per, tk.n);
  if (tk.mode == 0) {
    for (int i = beg + t; i < end; i += 256) {
      int s = tk.k1[i], d = tk.k2[i];
      int pa = atomicAdd(&curA[s >> tk.shift], 1);
      tk.o1h[pa] = (unsigned short)(s & tk.mask);
      int pb = atomicAdd(&curB[d >> tk.shift], 1);
      tk.o2[pb] = ((unsigned int)(d & tk.mask) << 17) | (unsigned int)s;
    }
  } else {
    for (int i = beg + t; i < end; i += 256) {
      int pa = atomicAdd(&curA[tk.k1[i] >> tk.shift], 1);
      tk.o1i[i] = pa;
    }
  }
}

// fused level-2: per level-1 bin, count -> block-local exclusive scan ->
// rowptr/nd/ns -> CSR col scatter.  No global scan needed: bin b's edges are
// contiguous in the level-1 output and bin b covers nodes [b*fine,(b+1)*fine).
__global__ __launch_bounds__(256) void k_l2fused(FZ P) {
  __shared__ int bins[512];
  __shared__ int pos[512];
  __shared__ int wsum[4];
  int b = blockIdx.x, t = threadIdx.x, ty = blockIdx.y;
  if (ty < 2) {
    FS tk = P.s[ty];
    for (int f = t; f < tk.fine; f += 256) bins[f] = 0;
    __syncthreads();
    int beg = tk.base[b * NBLK];
    int end = (b == NBLK - 1) ? tk.n : tk.base[(b + 1) * NBLK];
    for (int i = beg + t; i < end; i += 256)
      atomicAdd(&bins[tk.lows[i]], 1);
    __syncthreads();
    int v0 = b * tk.fine;
    for (int f = t; f < tk.fine; f += 256)
      tk.ns[v0 + f] = rsqrtf(fmaxf((float)bins[f], 1.f));
  } else {
    FD tk = P.d[ty - 2];
    for (int f = t; f < tk.fine; f += 256) bins[f] = 0;
    __syncthreads();
    int beg = tk.base[b * NBLK];
    int end = (b == NBLK - 1) ? tk.n : tk.base[(b + 1) * NBLK];
    for (int i = beg + t; i < end; i += 256)
      atomicAdd(&bins[tk.pk[i] >> 17], 1);
    __syncthreads();
    // block-local exclusive scan of bins -> pos, seeded with segment base
    int lane = t & 63, wid = t >> 6;
    int c = (tk.fine + 255) >> 8;          // bins per thread: 1 or 2
    int i0 = t * c;
    int vc[2] = {0, 0};
    int s = 0;
#pragma unroll
    for (int q = 0; q < 2; ++q) {
      if (q < c && i0 + q < tk.fine) { vc[q] = bins[i0 + q]; s += vc[q]; }
    }
    int inc = s;
    for (int dd = 1; dd < 64; dd <<= 1) {
      int u = __shfl_up(inc, dd, 64);
      if (lane >= dd) inc += u;
    }
    if (lane == 63) wsum[wid] = inc;
    __syncthreads();
    int woff = 0;
    for (int w = 0; w < wid; ++w) woff += wsum[w];
    int ex = beg + woff + inc - s;
#pragma unroll
    for (int q = 0; q < 2; ++q) {
      if (q < c && i0 + q < tk.fine) { pos[i0 + q] = ex; ex += vc[q]; }
    }
    __syncthreads();
    // emit rowptr + nd (before pos is consumed as a cursor)
    int v0 = b * tk.fine;
    for (int f = t; f < tk.fine; f += 256) {
      tk.rowptr[v0 + f] = pos[f];
      tk.nd[v0 + f] = rsqrtf(fmaxf((float)bins[f], 1.f));
    }
    if (b == NBLK - 1 && t == 0) tk.rowptr[tk.nnodes] = tk.n;
    __syncthreads();
    // pass 2: scatter CSR col
    for (int i = beg + t; i < end; i += 256) {
      unsigned int pk = tk.pk[i];
      int p = atomicAdd(&pos[pk >> 17], 1);
      tk.col[p] = (int)(pk & 0x1FFFFu);
    }
  }
}

// ---------------- towers ------------------------------------------------------

// Pack W (K x 128, fp32) into MFMA-B-fragment order, fp16:
//   out[((kc*8+nt)*64 + lane)*8 + e] = W[kc*32 + (lane>>4)*8 + e][nt*16 + (lane&15)]
__global__ __launch_bounds__(256) void k_wpack(W4 P) {
  WPk tk = P.t[blockIdx.y];
  int f = blockIdx.x;                       // fragment id 0..31
  int kch = (tk.K + 31) >> 5;
  if (f >= (kch << 3)) return;
  int kc = f >> 3, nt = f & 7;
  int t = threadIdx.x;
  int l = t & 63, e0 = (t >> 6) << 1;       // each thread handles 2 e-slots
  int col = (nt << 4) + (l & 15);
  int kb = (kc << 5) + ((l >> 4) << 3);
#pragma unroll
  for (int e = e0; e < e0 + 2; ++e) {
    int k = kb + e;
    float v = (k < tk.K) ? tk.W[(size_t)k * D + col] : 0.f;
    tk.out[(((size_t)f * 64 + l) << 3) + e] = (_Float16)v;
  }
}

// h[v,:] = fp16( ns[v] * (x[v,:] @ W) ) via mfma_f32_16x16x32_f16.
// 128 nodes per 512-thread block (8 waves); wave w owns 16 nodes (1 M-tile).
// All 4 A-fragments held in registers; accumulators processed in 2 nt-groups
// of 4 to keep register pressure <=64 VGPR -> 8 waves/SIMD occupancy.
__global__ __launch_bounds__(512, 8) void k_nl_gemm(GemP P) {
  __shared__ __align__(16) _Float16 Bs[32 * 64 * 8];   // 32 KB
  int bx = blockIdx.x;
  GTask tk;
  int v0;
  if (bx < P.nb0) { tk = P.t[0]; v0 = bx * 128; }
  else            { tk = P.t[1]; v0 = (bx - P.nb0) * 128; }
  const int K = tk.K;
  const int kch = (K + 31) >> 5;            // 4 (K=128) or 3 (K=74)
  int t = threadIdx.x, w = t >> 6, l = t & 63;

  // stage packed W into LDS (linear copy)
  {
    const uint4* src = (const uint4*)tk.Wp;
    uint4* dst = (uint4*)Bs;
    int n16 = kch << 9;                     // kch*8 frags * 64 lanes
    for (int i = t; i < n16; i += 512) dst[i] = src[i];
  }
  __syncthreads();

  int row = l & 15;
  int ks = (l >> 4) << 3;                   // k offset within 32-chunk
  int m0 = v0 + (w << 4);                   // 16 nodes per wave

  // load ALL A fragments for this wave's 16 rows (<=16 VGPR)
  half8 a[4];
  if (tk.xh) {                              // fp16 input, direct 16B fragments
    const _Float16* x0 = (const _Float16*)tk.x + (size_t)(m0 + row) * D + ks;
#pragma unroll
    for (int kc = 0; kc < 4; ++kc)
      a[kc] = *(const half8*)(x0 + (kc << 5));
  } else if (K == D) {                      // fp32 dense K=128
    const float* x0 = (const float*)tk.x + (size_t)(m0 + row) * D + ks;
#pragma unroll
    for (int kc = 0; kc < 4; ++kc) {
      float4 p0 = *(const float4*)(x0 + (kc << 5));
      float4 p1 = *(const float4*)(x0 + (kc << 5) + 4);
      a[kc][0] = (_Float16)p0.x; a[kc][1] = (_Float16)p0.y;
      a[kc][2] = (_Float16)p0.z; a[kc][3] = (_Float16)p0.w;
      a[kc][4] = (_Float16)p1.x; a[kc][5] = (_Float16)p1.y;
      a[kc][6] = (_Float16)p1.z; a[kc][7] = (_Float16)p1.w;
    }
  } else {                                  // K=74: guarded scalar, zero-padded
    const float* x0 = (const float*)tk.x + (size_t)(m0 + row) * K + ks;
#pragma unroll
    for (int kc = 0; kc < 3; ++kc)
#pragma unroll
      for (int e = 0; e < 8; ++e) {
        int k = (kc << 5) + ks + e;
        a[kc][e] = (k < K) ? (_Float16)x0[(kc << 5) + e] : (_Float16)0.f;
      }
#pragma unroll
    for (int e = 0; e < 8; ++e) a[3][e] = (_Float16)0.f;
  }

  int rr = (l >> 4) << 2;
  int c0 = l & 15;
  int vb = m0 + rr;
  float s0 = tk.ns[vb], s1 = tk.ns[vb + 1];
  float s2 = tk.ns[vb + 2], s3 = tk.ns[vb + 3];

  f32x4 zero = {0.f, 0.f, 0.f, 0.f};
#pragma unroll
  for (int ntg = 0; ntg < 2; ++ntg) {
    f32x4 acc[4];
#pragma unroll
    for (int q = 0; q < 4; ++q) acc[q] = zero;
#pragma unroll
    for (int nt4 = 0; nt4 < 4; ++nt4) {
      int nt = (ntg << 2) + nt4;
#pragma unroll
      for (int kc = 0; kc < 4; ++kc) {
        if (kc < kch) {
          half8 b = *(const half8*)&Bs[(size_t)((((kc << 3) + nt) << 6) + l) << 3];
          acc[nt4] = __builtin_amdgcn_mfma_f32_16x16x32_f16(a[kc], b, acc[nt4], 0, 0, 0);
        }
      }
    }
    // epilogue: C/D layout col=lane&15, row=(lane>>4)*4+reg
#pragma unroll
    for (int nt4 = 0; nt4 < 4; ++nt4) {
      int nt = (ntg << 2) + nt4;
      __half* hp = tk.h + (size_t)vb * D + (nt << 4) + c0;
      hp[0]     = __float2half_rn(acc[nt4][0] * s0);
      hp[D]     = __float2half_rn(acc[nt4][1] * s1);
      hp[2 * D] = __float2half_rn(acc[nt4][2] * s2);
      hp[3 * D] = __float2half_rn(acc[nt4][3] * s3);
    }
  }
}

// ---- aggregation: wave-per-node (grid-stride), 16 lanes x 8 feats (16B),
//      4 rows/instr, 32 edges per window (8 gathers in flight per lane).
//      Optional perm[] permutes the OUTPUT row (graph-sorted m2 for k_head).
__global__ __launch_bounds__(256) void k_aggregate(AggP P) {
  int wid = threadIdx.x >> 6;
  int lane = threadIdx.x & 63;
  int f0 = (lane & 15) * 8;
  int rsel = lane >> 4;
  int nw = (int)gridDim.x * 4;

  for (int gv = blockIdx.x * 4 + wid; gv < P.ntot; gv += nw) {
    ATask tk;
    int v;
    if (gv < P.np) { tk = P.t[0]; v = gv; }
    else           { tk = P.t[1]; v = gv - P.np; }
    int beg = tk.rowptr[v], end = tk.rowptr[v + 1];
    const __half* h = tk.h;
    const int* col = tk.col;

    float acc[8];
#pragma unroll
    for (int k = 0; k < 8; ++k) acc[k] = 0.f;

    for (int j = beg; j < end; j += 32) {
      int cc[8];
#pragma unroll
      for (int q = 0; q < 8; ++q) {
        int jj = j + 4 * q + rsel;
        cc[q] = (jj < end) ? col[jj] : -1;
      }
#pragma unroll
      for (int q = 0; q < 8; ++q) {
        if (cc[q] >= 0) {
          uint4 r = *(const uint4*)&h[(size_t)cc[q] * D + f0];
          const __half2* p = (const __half2*)&r;
#pragma unroll
          for (int k = 0; k < 4; ++k) {
            float2 f = __half22float2(p[k]);
            acc[2 * k] += f.x; acc[2 * k + 1] += f.y;
          }
        }
      }
    }

#pragma unroll
    for (int k = 0; k < 8; ++k) {
      acc[k] += __shfl_down(acc[k], 32, 64);
      acc[k] += __shfl_down(acc[k], 16, 64);
    }

    if (rsel == 0) {
      float s = tk.nd[v];
      float4 b0 = *(const float4*)&tk.b[f0];
      float4 b1 = *(const float4*)&tk.b[f0 + 4];
      float r[8];
      r[0] = fmaxf(fmaf(acc[0], s, b0.x), 0.f);
      r[1] = fmaxf(fmaf(acc[1], s, b0.y), 0.f);
      r[2] = fmaxf(fmaf(acc[2], s, b0.z), 0.f);
      r[3] = fmaxf(fmaf(acc[3], s, b0.w), 0.f);
      r[4] = fmaxf(fmaf(acc[4], s, b1.x), 0.f);
      r[5] = fmaxf(fmaf(acc[5], s, b1.y), 0.f);
      r[6] = fmaxf(fmaf(acc[6], s, b1.z), 0.f);
      r[7] = fmaxf(fmaf(acc[7], s, b1.w), 0.f);
      int ov = tk.perm ? tk.perm[v] : v;
      if (tk.halfOut) {
        union { __half2 h2[4]; uint4 u; } pk;
#pragma unroll
        for (int k = 0; k < 4; ++k) {
          pk.h2[k].x = __float2half_rn(r[2 * k]);
          pk.h2[k].y = __float2half_rn(r[2 * k + 1]);
        }
        *(uint4*)&((__half*)tk.out)[(size_t)ov * D + f0] = pk.u;
      } else {
        float4 o0 = {r[0], r[1], r[2], r[3]};
        float4 o1 = {r[4], r[5], r[6], r[7]};
        *(float4*)&((float*)tk.out)[(size_t)ov * D + f0] = o0;
        *(float4*)&((float*)tk.out)[(size_t)ov * D + f0 + 4] = o1;
      }
    }
  }
}

__device__ __forceinline__ void acc_half4(float4& a, const __half* p) {
  uint2 r = *(const uint2*)p;
  __half2 q0 = *(__half2*)&r.x;
  __half2 q1 = *(__half2*)&r.y;
  float2 f0 = __half22float2(q0);
  float2 f1 = __half22float2(q1);
  a.x += f0.x; a.y += f0.y; a.z += f1.x; a.w += f1.y;
}

// mean over graph-sorted rows [beg,end) of x -> dst[0..127] (in LDS)
__device__ __forceinline__ void block_mean_128(const __half* x, int beg, int end,
                                               float* dst, float (*sred)[128]) {
  int t = threadIdx.x;
  int slot = t >> 5;
  int c = (t & 31) * 4;
  float4 a0 = make_float4(0.f, 0.f, 0.f, 0.f);
  float4 a1 = make_float4(0.f, 0.f, 0.f, 0.f);
  int j = beg + slot;
  for (; j + 8 < end; j += 16) {
    acc_half4(a0, x + (size_t)j * D + c);
    acc_half4(a1, x + (size_t)(j + 8) * D + c);
  }
  if (j < end)
    acc_half4(a0, x + (size_t)j * D + c);
  a0.x += a1.x; a0.y += a1.y; a0.z += a1.z; a0.w += a1.w;

  a0.x += __shfl_down(a0.x, 32, 64);
  a0.y += __shfl_down(a0.y, 32, 64);
  a0.z += __shfl_down(a0.z, 32, 64);
  a0.w += __shfl_down(a0.w, 32, 64);

  int wid = t >> 6, lane = t & 63;
  if (lane < 32) *(float4*)&sred[wid][lane * 4] = a0;
  __syncthreads();
  if (t < 32) {
    float4 s0 = *(const float4*)&sred[0][t * 4];
    float4 s1 = *(const float4*)&sred[1][t * 4];
    float4 s2 = *(const float4*)&sred[2][t * 4];
    float4 s3 = *(const float4*)&sred[3][t * 4];
    float inv = 1.f / fmaxf((float)(end - beg), 1.f);
    float4 r;
    r.x = (s0.x + s1.x + s2.x + s3.x) * inv;
    r.y = (s0.y + s1.y + s2.y + s3.y) * inv;
    r.z = (s0.z + s1.z + s2.z + s3.z) * inv;
    r.w = (s0.w + s1.w + s2.w + s3.w) * inv;
    *(float4*)&dst[t * 4] = r;
  }
  __syncthreads();
}

// fused readout: per graph, compound mean + protein mean + 2-layer MLP
__global__ __launch_bounds__(256) void k_head(HeadP P) {
  __shared__ float xs[256];
  __shared__ float sred[4][128];
  int g = blockIdx.x, t = threadIdx.x;
  int nb = (int)gridDim.x;

  int cb = P.cbase[g * NBLK];
  int ce = (g == nb - 1) ? P.cn : P.cbase[(g + 1) * NBLK];
  block_mean_128(P.cx, cb, ce, xs, sred);
  int pb = P.pbase[g * NBLK];
  int pe = (g == nb - 1) ? P.pn : P.pbase[(g + 1) * NBLK];
  block_mean_128(P.px, pb, pe, xs + 128, sred);

  // MLP: hidden 128; 256 threads -> each half-k range per hidden unit
  int hu = t & 127, half = t >> 7;
  float acc = 0.f;
  int k0 = half * 128;
  for (int k = k0; k < k0 + 128; ++k)
    acc = fmaf(xs[k], P.Wf1[k * D + hu], acc);
  float* hacc = &sred[2][0];   // 256 floats
  float* red = &sred[0][0];    // 128 floats
  hacc[t] = acc;
  __syncthreads();
  if (t < 128) {
    float hv = fmaxf(hacc[t] + hacc[t + 128] + P.bf1[t], 0.f);
    red[t] = hv * P.Wf2[t];
  }
  for (int d = 64; d > 0; d >>= 1) {
    __syncthreads();
    if (t < d) red[t] += red[t + d];
  }
  if (t == 0) P.out[g] = red[0] + P.bf2[0];
}

// ---------------- launch ------------------------------------------------------

extern "C" void kernel_launch(void* const* d_in, const int* in_sizes, int n_in,
                              void* d_out, int out_size, void* d_ws, size_t ws_size,
                              hipStream_t stream) {
  const float* compound_feat = (const float*)d_in[0];
  const float* protein_feat  = (const float*)d_in[1];
  const int* c_src = (const int*)d_in[2];
  const int* c_dst = (const int*)d_in[3];
  const int* p_src = (const int*)d_in[4];
  const int* p_dst = (const int*)d_in[5];
  const int* c_gid = (const int*)d_in[6];
  const int* p_gid = (const int*)d_in[7];
  const float* Wc1 = (const float*)d_in[8];  const float* bc1 = (const float*)d_in[9];
  const float* Wc2 = (const float*)d_in[10]; const float* bc2 = (const float*)d_in[11];
  const float* Wp1 = (const float*)d_in[12]; const float* bp1 = (const float*)d_in[13];
  const float* Wp2 = (const float*)d_in[14]; const float* bp2 = (const float*)d_in[15];
  const float* Wf1 = (const float*)d_in[16]; const float* bf1 = (const float*)d_in[17];
  const float* Wf2 = (const float*)d_in[18]; const float* bf2 = (const float*)d_in[19];
  float* out = (float*)d_out;

  const int EC = in_sizes[2], EP = in_sizes[4];
  const int NC = in_sizes[6], NP = in_sizes[7];
  const int B  = out_size;
  const int KC = in_sizes[0] / NC;                 // 74
  const int cshift = __builtin_ctz(NC / 256), cfine = NC / 256;
  const int pshift = __builtin_ctz(NP / 256), pfine = NP / 256;
  const int HN = 256 * NBLK;

  char* ws = (char*)d_ws;
  size_t off = 0;
  auto alloc = [&](size_t bytes) -> void* {
    void* p = ws + off;
    off += (bytes + 255) & ~(size_t)255;
    return p;
  };

  int* H0 = (int*)alloc((size_t)HN * 4);
  int* H1 = (int*)alloc((size_t)HN * 4);
  int* H2 = (int*)alloc((size_t)HN * 4);
  int* H3 = (int*)alloc((size_t)HN * 4);
  int* H4 = (int*)alloc((size_t)HN * 4);
  int* H5 = (int*)alloc((size_t)HN * 4);
  int* partH = (int*)alloc((size_t)6 * 32 * 4);
  unsigned short* tmps_c = (unsigned short*)alloc((size_t)EC * 2);
  unsigned short* tmps_p = (unsigned short*)alloc((size_t)EP * 2);
  unsigned int* tmpe_c = (unsigned int*)alloc((size_t)EC * 4);
  unsigned int* tmpe_p = (unsigned int*)alloc((size_t)EP * 4);
  float* c_ns = (float*)alloc((size_t)NC * 4);
  float* c_nd = (float*)alloc((size_t)NC * 4);
  float* p_ns = (float*)alloc((size_t)NP * 4);
  float* p_nd = (float*)alloc((size_t)NP * 4);
  int* c_rowptr = (int*)alloc((size_t)(NC + 1) * 4);
  int* p_rowptr = (int*)alloc((size_t)(NP + 1) * 4);
  int* c_col   = (int*)alloc((size_t)EC * 4);
  int* p_col   = (int*)alloc((size_t)EP * 4);
  int* c_perm = (int*)alloc((size_t)NC * 4);
  int* p_perm = (int*)alloc((size_t)NP * 4);
  __half* c_h  = (__half*)alloc((size_t)NC * D * 2);
  __half* c_m1 = (__half*)alloc((size_t)NC * D * 2);
  __half* c_m2 = (__half*)alloc((size_t)NC * D * 2);
  __half* p_h  = (__half*)alloc((size_t)NP * D * 2);
  __half* p_m1 = (__half*)alloc((size_t)NP * D * 2);
  __half* p_m2 = (__half*)alloc((size_t)NP * D * 2);
  _Float16* wp_p1 = (_Float16*)alloc((size_t)32 * 1024);
  _Float16* wp_c1 = (_Float16*)alloc((size_t)32 * 1024);
  _Float16* wp_p2 = (_Float16*)alloc((size_t)32 * 1024);
  _Float16* wp_c2 = (_Float16*)alloc((size_t)32 * 1024);
  (void)ws_size; (void)n_in;

  // 0) pack the four W matrices into fp16 MFMA fragment order (independent)
  {
    W4 PW = {{{Wp1, wp_p1, D}, {Wc1, wp_c1, KC}, {Wp2, wp_p2, D}, {Wc2, wp_c2, D}}};
    k_wpack<<<dim3(32, 4), 256, 0, stream>>>(PW);
  }
  // 1) all six 256-bin histograms
  {
    H6 P = {{{c_src, EC, cshift, H0}, {c_dst, EC, cshift, H1}, {c_gid, NC, 0, H2},
             {p_src, EP, pshift, H3}, {p_dst, EP, pshift, H4}, {p_gid, NP, 0, H5}}};
    k_hist_all<<<dim3(NBLK, 6), 256, 0, stream>>>(P);
  }
  // 2) scan the six H arrays in place
  {
    SP6 Pp = {{{H0, HN, partH + 0}, {H1, HN, partH + 32}, {H2, HN, partH + 64},
               {H3, HN, partH + 96}, {H4, HN, partH + 128}, {H5, HN, partH + 160}}};
    k_scan_part_all<<<dim3(16, 6), 256, 0, stream>>>(Pp);
    SD6 Pd = {{{H0, HN, partH + 0, H0, nullptr}, {H1, HN, partH + 32, H1, nullptr},
               {H2, HN, partH + 64, H2, nullptr}, {H3, HN, partH + 96, H3, nullptr},
               {H4, HN, partH + 128, H4, nullptr}, {H5, HN, partH + 160, H5, nullptr}}};
    k_scan_down_all<<<dim3(16, 6), 256, 0, stream>>>(Pd);
  }
  // 3) level-1 scatters (packed edge sorts + gid inverse-permutations)
  {
    Sc4 P = {{{c_src, c_dst, EC, cshift, cfine - 1, H0, H1, tmps_c, nullptr, tmpe_c, 0},
              {p_src, p_dst, EP, pshift, pfine - 1, H3, H4, tmps_p, nullptr, tmpe_p, 0},
              {c_gid, nullptr, NC, 0, 0, H2, nullptr, nullptr, c_perm, nullptr, 1},
              {p_gid, nullptr, NP, 0, 0, H5, nullptr, nullptr, p_perm, nullptr, 1}}};
    k_scatter_all<<<dim3(NBLK, 4), 256, 0, stream>>>(P);
  }
  // 4) fused level-2: counts -> ns / (rowptr, nd, col)
  {
    FZ PF = {{{tmps_c, H0, EC, cfine, c_ns}, {tmps_p, H3, EP, pfine, p_ns}},
             {{tmpe_c, H1, EC, cfine, c_rowptr, c_col, c_nd, NC},
              {tmpe_p, H4, EP, pfine, p_rowptr, p_col, p_nd, NP}}};
    k_l2fused<<<dim3(NBLK, 4), 256, 0, stream>>>(PF);
  }

  // ---- towers (flattened grids: protein first) ----
  const int gnb = NP / 128 + NC / 128;
  const int ntot = NP + NC;
  const int anb = min((ntot + 3) / 4, 8192);   // grid-stride persistent waves
  {
    GemP P = {{{protein_feat, p_ns, wp_p1, p_h, D, 0},
               {compound_feat, c_ns, wp_c1, c_h, KC, 0}}, NP / 128};
    k_nl_gemm<<<gnb, 512, 0, stream>>>(P);
  }
  {
    AggP P = {{{p_h, p_rowptr, p_col, p_nd, bp1, nullptr, p_m1, 1},
               {c_h, c_rowptr, c_col, c_nd, bc1, nullptr, c_m1, 1}}, NP, ntot};
    k_aggregate<<<anb, 256, 0, stream>>>(P);
  }
  {
    GemP P = {{{p_m1, p_ns, wp_p2, p_h, D, 1}, {c_m1, c_ns, wp_c2, c_h, D, 1}}, NP / 128};
    k_nl_gemm<<<gnb, 512, 0, stream>>>(P);
  }
  {
    // layer-2 aggregate writes m2 rows permuted into graph-sorted order
    AggP P = {{{p_h, p_rowptr, p_col, p_nd, bp2, p_perm, p_m2, 1},
               {c_h, c_rowptr, c_col, c_nd, bc2, c_perm, c_m2, 1}}, NP, ntot};
    k_aggregate<<<anb, 256, 0, stream>>>(P);
  }
  // 5) fused readout: means + predictor MLP
  {
    HeadP PH = {c_m2, H2, NC, p_m2, H5, NP, Wf1, bf1, Wf2, bf2, out};
    k_head<<<B, 256, 0, stream>>>(PH);
  }
}

// Round 8
// 493.532 us; speedup vs baseline: 1.0739x; 1.0025x over previous
//
#include <hip/hip_runtime.h>
#include <hip/hip_fp16.h>

#define D 128
#define SCH 4096    // elements per scan block
#define NBLK 256    // blocks per level-1 distribution

typedef _Float16 half8 __attribute__((ext_vector_type(8)));
typedef float f32x4 __attribute__((ext_vector_type(4)));

// ---------------- task structs (passed by value) -----------------------------
struct HTask { const int* keys; int n; int shift; int* H; };
struct WPk { const float* W; _Float16* out; int K; };
struct HW6 { HTask t[6]; WPk w[4]; };

struct SPTask { const int* in; int n; int* part; };
struct SP6 { SPTask t[6]; };

struct SDTask { const int* in; int n; const int* part; int* out; int* total; };
struct SD6 { SDTask t[6]; };

struct ScTask { const int* k1; const int* k2; int n; int shift; int mask;
                const int* base1; const int* base2;
                unsigned short* o1h; int* o1i; unsigned int* o2; int mode; };
struct Sc4 { ScTask t[4]; };

struct FS { const unsigned short* lows; const int* base; int n; int fine; float* ns; };
struct FD { const unsigned int* pk; const int* base; int n; int fine;
            int* rowptr; int* col; float* nd; int nnodes; };
struct FZ { FS s[2]; FD d[2]; };

struct GTask { const void* x; const float* ns; const _Float16* Wp; __half* h;
               int K; int xh; };
struct GemP { GTask t[2]; int nb0; };

struct ATask { const __half* h; const int* rowptr; const int* col;
               const float* nd; const float* b; const int* perm;
               void* out; int halfOut; };
struct AggP { ATask t[2]; int np; int ntot; };

struct HeadP { const __half* cx; const int* cbase; int cn;
               const __half* px; const int* pbase; int pn;
               const float* Wf1; const float* bf1; const float* Wf2; const float* bf2;
               float* out; };

// ---------------- fused preprocessing ----------------------------------------

// y<6: 256-bin histograms.  y==6: pack the four W matrices into MFMA-B
// fragment order, fp16 (independent work folded into the same launch).
__global__ __launch_bounds__(256) void k_hist_all(HW6 P) {
  int t = threadIdx.x;
  if (blockIdx.y == 6) {
    int bx = blockIdx.x;
    if (bx >= 128) return;
    WPk tk = P.w[bx >> 5];
    int f = bx & 31;                        // fragment id 0..31
    int kch = (tk.K + 31) >> 5;
    if (f >= (kch << 3)) return;
    int kc = f >> 3, nt = f & 7;
    int l = t & 63, e0 = (t >> 6) << 1;
    int col = (nt << 4) + (l & 15);
    int kb = (kc << 5) + ((l >> 4) << 3);
#pragma unroll
    for (int e = e0; e < e0 + 2; ++e) {
      int k = kb + e;
      float v = (k < tk.K) ? tk.W[(size_t)k * D + col] : 0.f;
      tk.out[(((size_t)f * 64 + l) << 3) + e] = (_Float16)v;
    }
    return;
  }
  HTask tk = P.t[blockIdx.y];
  __shared__ int bins[256];
  int blk = blockIdx.x;
  bins[t] = 0;
  __syncthreads();
  int per = (tk.n + NBLK - 1) / NBLK;
  int beg = blk * per, end = min(beg + per, tk.n);
  for (int i = beg + t; i < end; i += 256)
    atomicAdd(&bins[tk.keys[i] >> tk.shift], 1);
  __syncthreads();
  tk.H[t * NBLK + blk] = bins[t];
}

__global__ __launch_bounds__(256) void k_scan_part_all(SP6 P) {
  SPTask tk = P.t[blockIdx.y];
  int b = blockIdx.x, t = threadIdx.x;
  int base = b * SCH;
  int s = 0;
  for (int i = t; i < SCH; i += 256) {
    int idx = base + i;
    if (idx < tk.n) s += tk.in[idx];
  }
  __shared__ int red[256];
  red[t] = s;
  __syncthreads();
  for (int d = 128; d > 0; d >>= 1) {
    if (t < d) red[t] += red[t + d];
    __syncthreads();
  }
  if (t == 0) tk.part[b] = red[0];
}

__global__ __launch_bounds__(256) void k_scan_down_all(SD6 P) {
  SDTask tk = P.t[blockIdx.y];
  int b = blockIdx.x, t = threadIdx.x;
  int lane = t & 63, wid = t >> 6;
  __shared__ int wsum[4];
  if (b == 0 && t == 0 && tk.total) {
    int s = 0;
    for (int w = 0; w < (int)gridDim.x; ++w) s += tk.part[w];
    *tk.total = s;
  }
  int offset = 0;
  for (int w = 0; w < b; ++w) offset += tk.part[w];
  int base = b * SCH;
  if (base >= tk.n) return;
  int idx0 = base + t * 16;
  int v[16];
  int s = 0;
#pragma unroll
  for (int i = 0; i < 16; ++i) {
    int idx = idx0 + i;
    v[i] = (idx < tk.n) ? tk.in[idx] : 0;
    s += v[i];
  }
  int inc = s;
  for (int d = 1; d < 64; d <<= 1) {
    int u = __shfl_up(inc, d, 64);
    if (lane >= d) inc += u;
  }
  if (lane == 63) wsum[wid] = inc;
  __syncthreads();
  int woff = 0;
  for (int w = 0; w < wid; ++w) woff += wsum[w];
  int ex = offset + woff + inc - s;
#pragma unroll
  for (int i = 0; i < 16; ++i) {
    int idx = idx0 + i;
    if (idx < tk.n) tk.out[idx] = ex;
    ex += v[i];
  }
}

// level-1 scatter.  mode 0: edge sort — writes low-bits of src (u16) into
// src-sorted order and (dst_low<<17 | src) packed u32 into dst-sorted order.
// mode 1: gid inverse permutation perm[i] = graph-sorted position of node i.
__global__ __launch_bounds__(256) void k_scatter_all(Sc4 P) {
  ScTask tk = P.t[blockIdx.y];
  __shared__ int curA[256], curB[256];
  int blk = blockIdx.x, t = threadIdx.x;
  curA[t] = tk.base1[t * NBLK + blk];
  if (tk.mode == 0) curB[t] = tk.base2[t * NBLK + blk];
  __syncthreads();
  int per = (tk.n + NBLK - 1) / NBLK;
  int beg = blk * per, end = min(beg + per, tk.n);
  if (tk.mode == 0) {
    for (int i = beg + t; i < end; i += 256) {
      int s = tk.k1[i], d = tk.k2[i];
      int pa = atomicAdd(&curA[s >> tk.shift], 1);
      tk.o1h[pa] = (unsigned short)(s & tk.mask);
      int pb = atomicAdd(&curB[d >> tk.shift], 1);
      tk.o2[pb] = ((unsigned int)(d & tk.mask) << 17) | (unsigned int)s;
    }
  } else {
    for (int i = beg + t; i < end; i += 256) {
      int pa = atomicAdd(&curA[tk.k1[i] >> tk.shift], 1);
      tk.o1i[i] = pa;
    }
  }
}

// fused level-2: per level-1 bin, count -> block-local exclusive scan ->
// rowptr/nd/ns -> CSR col scatter.  No global scan needed: bin b's edges are
// contiguous in the level-1 output and bin b covers nodes [b*fine,(b+1)*fine).
__global__ __launch_bounds__(256) void k_l2fused(FZ P) {
  __shared__ int bins[512];
  __shared__ int pos[512];
  __shared__ int wsum[4];
  int b = blockIdx.x, t = threadIdx.x, ty = blockIdx.y;
  if (ty < 2) {
    FS tk = P.s[ty];
    for (int f = t; f < tk.fine; f += 256) bins[f] = 0;
    __syncthreads();
    int beg = tk.base[b * NBLK];
    int end = (b == NBLK - 1) ? tk.n : tk.base[(b + 1) * NBLK];
    for (int i = beg + t; i < end; i += 256)
      atomicAdd(&bins[tk.lows[i]], 1);
    __syncthreads();
    int v0 = b * tk.fine;
    for (int f = t; f < tk.fine; f += 256)
      tk.ns[v0 + f] = rsqrtf(fmaxf((float)bins[f], 1.f));
  } else {
    FD tk = P.d[ty - 2];
    for (int f = t; f < tk.fine; f += 256) bins[f] = 0;
    __syncthreads();
    int beg = tk.base[b * NBLK];
    int end = (b == NBLK - 1) ? tk.n : tk.base[(b + 1) * NBLK];
    for (int i = beg + t; i < end; i += 256)
      atomicAdd(&bins[tk.pk[i] >> 17], 1);
    __syncthreads();
    // block-local exclusive scan of bins -> pos, seeded with segment base
    int lane = t & 63, wid = t >> 6;
    int c = (tk.fine + 255) >> 8;          // bins per thread: 1 or 2
    int i0 = t * c;
    int vc[2] = {0, 0};
    int s = 0;
#pragma unroll
    for (int q = 0; q < 2; ++q) {
      if (q < c && i0 + q < tk.fine) { vc[q] = bins[i0 + q]; s += vc[q]; }
    }
    int inc = s;
    for (int dd = 1; dd < 64; dd <<= 1) {
      int u = __shfl_up(inc, dd, 64);
      if (lane >= dd) inc += u;
    }
    if (lane == 63) wsum[wid] = inc;
    __syncthreads();
    int woff = 0;
    for (int w = 0; w < wid; ++w) woff += wsum[w];
    int ex = beg + woff + inc - s;
#pragma unroll
    for (int q = 0; q < 2; ++q) {
      if (q < c && i0 + q < tk.fine) { pos[i0 + q] = ex; ex += vc[q]; }
    }
    __syncthreads();
    // emit rowptr + nd (before pos is consumed as a cursor)
    int v0 = b * tk.fine;
    for (int f = t; f < tk.fine; f += 256) {
      tk.rowptr[v0 + f] = pos[f];
      tk.nd[v0 + f] = rsqrtf(fmaxf((float)bins[f], 1.f));
    }
    if (b == NBLK - 1 && t == 0) tk.rowptr[tk.nnodes] = tk.n;
    __syncthreads();
    // pass 2: scatter CSR col
    for (int i = beg + t; i < end; i += 256) {
      unsigned int pk = tk.pk[i];
      int p = atomicAdd(&pos[pk >> 17], 1);
      tk.col[p] = (int)(pk & 0x1FFFFu);
    }
  }
}

// ---------------- towers ------------------------------------------------------

// h[v,:] = fp16( ns[v] * (x[v,:] @ W) ) via mfma_f32_16x16x32_f16.
// 128 nodes per 512-thread block (8 waves); wave w owns 16 nodes (1 M-tile).
// Epilogue stages each wave's 16x128 C tile in a private padded LDS buffer,
// then emits coalesced 16B stores (vs 32 scalar 2B stores per lane).
__global__ __launch_bounds__(512, 6) void k_nl_gemm(GemP P) {
  __shared__ __align__(16) _Float16 Bs[32 * 64 * 8];   // 32 KB
  __shared__ __align__(16) _Float16 Cs[8][16][72];     // 18 KB, padded rows
  int bx = blockIdx.x;
  GTask tk;
  int v0;
  if (bx < P.nb0) { tk = P.t[0]; v0 = bx * 128; }
  else            { tk = P.t[1]; v0 = (bx - P.nb0) * 128; }
  const int K = tk.K;
  const int kch = (K + 31) >> 5;            // 4 (K=128) or 3 (K=74)
  int t = threadIdx.x, w = t >> 6, l = t & 63;

  // stage packed W into LDS (linear copy)
  {
    const uint4* src = (const uint4*)tk.Wp;
    uint4* dst = (uint4*)Bs;
    int n16 = kch << 9;                     // kch*8 frags * 64 lanes
    for (int i = t; i < n16; i += 512) dst[i] = src[i];
  }
  __syncthreads();

  int row = l & 15;
  int ks = (l >> 4) << 3;                   // k offset within 32-chunk
  int m0 = v0 + (w << 4);                   // 16 nodes per wave

  // load ALL A fragments for this wave's 16 rows (<=16 VGPR)
  half8 a[4];
  if (tk.xh) {                              // fp16 input, direct 16B fragments
    const _Float16* x0 = (const _Float16*)tk.x + (size_t)(m0 + row) * D + ks;
#pragma unroll
    for (int kc = 0; kc < 4; ++kc)
      a[kc] = *(const half8*)(x0 + (kc << 5));
  } else if (K == D) {                      // fp32 dense K=128
    const float* x0 = (const float*)tk.x + (size_t)(m0 + row) * D + ks;
#pragma unroll
    for (int kc = 0; kc < 4; ++kc) {
      float4 p0 = *(const float4*)(x0 + (kc << 5));
      float4 p1 = *(const float4*)(x0 + (kc << 5) + 4);
      a[kc][0] = (_Float16)p0.x; a[kc][1] = (_Float16)p0.y;
      a[kc][2] = (_Float16)p0.z; a[kc][3] = (_Float16)p0.w;
      a[kc][4] = (_Float16)p1.x; a[kc][5] = (_Float16)p1.y;
      a[kc][6] = (_Float16)p1.z; a[kc][7] = (_Float16)p1.w;
    }
  } else {                                  // K=74: guarded scalar, zero-padded
    const float* x0 = (const float*)tk.x + (size_t)(m0 + row) * K + ks;
#pragma unroll
    for (int kc = 0; kc < 3; ++kc)
#pragma unroll
      for (int e = 0; e < 8; ++e) {
        int k = (kc << 5) + ks + e;
        a[kc][e] = (k < K) ? (_Float16)x0[(kc << 5) + e] : (_Float16)0.f;
      }
#pragma unroll
    for (int e = 0; e < 8; ++e) a[3][e] = (_Float16)0.f;
  }

  int rr = (l >> 4) << 2;
  int c0 = l & 15;
  int vb = m0 + rr;
  float s0 = tk.ns[vb], s1 = tk.ns[vb + 1];
  float s2 = tk.ns[vb + 2], s3 = tk.ns[vb + 3];

  f32x4 zero = {0.f, 0.f, 0.f, 0.f};
#pragma unroll
  for (int ntg = 0; ntg < 2; ++ntg) {
    f32x4 acc[4];
#pragma unroll
    for (int q = 0; q < 4; ++q) acc[q] = zero;
#pragma unroll
    for (int nt4 = 0; nt4 < 4; ++nt4) {
      int nt = (ntg << 2) + nt4;
#pragma unroll
      for (int kc = 0; kc < 4; ++kc) {
        if (kc < kch) {
          half8 b = *(const half8*)&Bs[(size_t)((((kc << 3) + nt) << 6) + l) << 3];
          acc[nt4] = __builtin_amdgcn_mfma_f32_16x16x32_f16(a[kc], b, acc[nt4], 0, 0, 0);
        }
      }
    }
    // stage C quadrant into this wave's LDS tile (rows 0..15, cols nt4*16+c0)
#pragma unroll
    for (int nt4 = 0; nt4 < 4; ++nt4) {
      int cc = (nt4 << 4) + c0;
      Cs[w][rr + 0][cc] = (_Float16)(acc[nt4][0] * s0);
      Cs[w][rr + 1][cc] = (_Float16)(acc[nt4][1] * s1);
      Cs[w][rr + 2][cc] = (_Float16)(acc[nt4][2] * s2);
      Cs[w][rr + 3][cc] = (_Float16)(acc[nt4][3] * s3);
    }
    // wave-private buffer: ds ops within a wave are ordered via lgkmcnt only.
    // coalesced write-out: 2 passes x 16B per lane, 128B-contiguous per 8 lanes
#pragma unroll
    for (int p = 0; p < 2; ++p) {
      int chunk = (p << 6) + l;
      int cr = chunk >> 3;                  // row 0..15
      int ch = chunk & 7;                   // 16B chunk within 64-col group
      half8 vv = *(const half8*)&Cs[w][cr][ch << 3];
      *(half8*)&tk.h[(size_t)(m0 + cr) * D + (ntg << 6) + (ch << 3)] = vv;
    }
  }
}

// ---- aggregation: wave-per-node (grid-stride), 16 lanes x 8 feats (16B),
//      4 rows/instr, 32 edges per window (8 gathers in flight per lane).
//      Optional perm[] permutes the OUTPUT row (graph-sorted m2 for k_head).
__global__ __launch_bounds__(256) void k_aggregate(AggP P) {
  int wid = threadIdx.x >> 6;
  int lane = threadIdx.x & 63;
  int f0 = (lane & 15) * 8;
  int rsel = lane >> 4;
  int nw = (int)gridDim.x * 4;

  for (int gv = blockIdx.x * 4 + wid; gv < P.ntot; gv += nw) {
    ATask tk;
    int v;
    if (gv < P.np) { tk = P.t[0]; v = gv; }
    else           { tk = P.t[1]; v = gv - P.np; }
    int beg = tk.rowptr[v], end = tk.rowptr[v + 1];
    const __half* h = tk.h;
    const int* col = tk.col;

    float acc[8];
#pragma unroll
    for (int k = 0; k < 8; ++k) acc[k] = 0.f;

    for (int j = beg; j < end; j += 32) {
      int cc[8];
#pragma unroll
      for (int q = 0; q < 8; ++q) {
        int jj = j + 4 * q + rsel;
        cc[q] = (jj < end) ? col[jj] : -1;
      }
#pragma unroll
      for (int q = 0; q < 8; ++q) {
        if (cc[q] >= 0) {
          uint4 r = *(const uint4*)&h[(size_t)cc[q] * D + f0];
          const __half2* p = (const __half2*)&r;
#pragma unroll
          for (int k = 0; k < 4; ++k) {
            float2 f = __half22float2(p[k]);
            acc[2 * k] += f.x; acc[2 * k + 1] += f.y;
          }
        }
      }
    }

#pragma unroll
    for (int k = 0; k < 8; ++k) {
      acc[k] += __shfl_down(acc[k], 32, 64);
      acc[k] += __shfl_down(acc[k], 16, 64);
    }

    if (rsel == 0) {
      float s = tk.nd[v];
      float4 b0 = *(const float4*)&tk.b[f0];
      float4 b1 = *(const float4*)&tk.b[f0 + 4];
      float r[8];
      r[0] = fmaxf(fmaf(acc[0], s, b0.x), 0.f);
      r[1] = fmaxf(fmaf(acc[1], s, b0.y), 0.f);
      r[2] = fmaxf(fmaf(acc[2], s, b0.z), 0.f);
      r[3] = fmaxf(fmaf(acc[3], s, b0.w), 0.f);
      r[4] = fmaxf(fmaf(acc[4], s, b1.x), 0.f);
      r[5] = fmaxf(fmaf(acc[5], s, b1.y), 0.f);
      r[6] = fmaxf(fmaf(acc[6], s, b1.z), 0.f);
      r[7] = fmaxf(fmaf(acc[7], s, b1.w), 0.f);
      int ov = tk.perm ? tk.perm[v] : v;
      if (tk.halfOut) {
        union { __half2 h2[4]; uint4 u; } pk;
#pragma unroll
        for (int k = 0; k < 4; ++k) {
          pk.h2[k].x = __float2half_rn(r[2 * k]);
          pk.h2[k].y = __float2half_rn(r[2 * k + 1]);
        }
        *(uint4*)&((__half*)tk.out)[(size_t)ov * D + f0] = pk.u;
      } else {
        float4 o0 = {r[0], r[1], r[2], r[3]};
        float4 o1 = {r[4], r[5], r[6], r[7]};
        *(float4*)&((float*)tk.out)[(size_t)ov * D + f0] = o0;
        *(float4*)&((float*)tk.out)[(size_t)ov * D + f0 + 4] = o1;
      }
    }
  }
}

__device__ __forceinline__ void acc_half4(float4& a, const __half* p) {
  uint2 r = *(const uint2*)p;
  __half2 q0 = *(__half2*)&r.x;
  __half2 q1 = *(__half2*)&r.y;
  float2 f0 = __half22float2(q0);
  float2 f1 = __half22float2(q1);
  a.x += f0.x; a.y += f0.y; a.z += f1.x; a.w += f1.y;
}

// mean over graph-sorted rows [beg,end) of x -> dst[0..127] (in LDS)
__device__ __forceinline__ void block_mean_128(const __half* x, int beg, int end,
                                               float* dst, float (*sred)[128]) {
  int t = threadIdx.x;
  int slot = t >> 5;
  int c = (t & 31) * 4;
  float4 a0 = make_float4(0.f, 0.f, 0.f, 0.f);
  float4 a1 = make_float4(0.f, 0.f, 0.f, 0.f);
  int j = beg + slot;
  for (; j + 8 < end; j += 16) {
    acc_half4(a0, x + (size_t)j * D + c);
    acc_half4(a1, x + (size_t)(j + 8) * D + c);
  }
  if (j < end)
    acc_half4(a0, x + (size_t)j * D + c);
  a0.x += a1.x; a0.y += a1.y; a0.z += a1.z; a0.w += a1.w;

  a0.x += __shfl_down(a0.x, 32, 64);
  a0.y += __shfl_down(a0.y, 32, 64);
  a0.z += __shfl_down(a0.z, 32, 64);
  a0.w += __shfl_down(a0.w, 32, 64);

  int wid = t >> 6, lane = t & 63;
  if (lane < 32) *(float4*)&sred[wid][lane * 4] = a0;
  __syncthreads();
  if (t < 32) {
    float4 s0 = *(const float4*)&sred[0][t * 4];
    float4 s1 = *(const float4*)&sred[1][t * 4];
    float4 s2 = *(const float4*)&sred[2][t * 4];
    float4 s3 = *(const float4*)&sred[3][t * 4];
    float inv = 1.f / fmaxf((float)(end - beg), 1.f);
    float4 r;
    r.x = (s0.x + s1.x + s2.x + s3.x) * inv;
    r.y = (s0.y + s1.y + s2.y + s3.y) * inv;
    r.z = (s0.z + s1.z + s2.z + s3.z) * inv;
    r.w = (s0.w + s1.w + s2.w + s3.w) * inv;
    *(float4*)&dst[t * 4] = r;
  }
  __syncthreads();
}

// fused readout: per graph, compound mean + protein mean + 2-layer MLP
__global__ __launch_bounds__(256) void k_head(HeadP P) {
  __shared__ float xs[256];
  __shared__ float sred[4][128];
  int g = blockIdx.x, t = threadIdx.x;
  int nb = (int)gridDim.x;

  int cb = P.cbase[g * NBLK];
  int ce = (g == nb - 1) ? P.cn : P.cbase[(g + 1) * NBLK];
  block_mean_128(P.cx, cb, ce, xs, sred);
  int pb = P.pbase[g * NBLK];
  int pe = (g == nb - 1) ? P.pn : P.pbase[(g + 1) * NBLK];
  block_mean_128(P.px, pb, pe, xs + 128, sred);

  // MLP: hidden 128; 256 threads -> each half-k range per hidden unit
  int hu = t & 127, half = t >> 7;
  float acc = 0.f;
  int k0 = half * 128;
  for (int k = k0; k < k0 + 128; ++k)
    acc = fmaf(xs[k], P.Wf1[k * D + hu], acc);
  float* hacc = &sred[2][0];   // 256 floats
  float* red = &sred[0][0];    // 128 floats
  hacc[t] = acc;
  __syncthreads();
  if (t < 128) {
    float hv = fmaxf(hacc[t] + hacc[t + 128] + P.bf1[t], 0.f);
    red[t] = hv * P.Wf2[t];
  }
  for (int d = 64; d > 0; d >>= 1) {
    __syncthreads();
    if (t < d) red[t] += red[t + d];
  }
  if (t == 0) P.out[g] = red[0] + P.bf2[0];
}

// ---------------- launch ------------------------------------------------------

extern "C" void kernel_launch(void* const* d_in, const int* in_sizes, int n_in,
                              void* d_out, int out_size, void* d_ws, size_t ws_size,
                              hipStream_t stream) {
  const float* compound_feat = (const float*)d_in[0];
  const float* protein_feat  = (const float*)d_in[1];
  const int* c_src = (const int*)d_in[2];
  const int* c_dst = (const int*)d_in[3];
  const int* p_src = (const int*)d_in[4];
  const int* p_dst = (const int*)d_in[5];
  const int* c_gid = (const int*)d_in[6];
  const int* p_gid = (const int*)d_in[7];
  const float* Wc1 = (const float*)d_in[8];  const float* bc1 = (const float*)d_in[9];
  const float* Wc2 = (const float*)d_in[10]; const float* bc2 = (const float*)d_in[11];
  const float* Wp1 = (const float*)d_in[12]; const float* bp1 = (const float*)d_in[13];
  const float* Wp2 = (const float*)d_in[14]; const float* bp2 = (const float*)d_in[15];
  const float* Wf1 = (const float*)d_in[16]; const float* bf1 = (const float*)d_in[17];
  const float* Wf2 = (const float*)d_in[18]; const float* bf2 = (const float*)d_in[19];
  float* out = (float*)d_out;

  const int EC = in_sizes[2], EP = in_sizes[4];
  const int NC = in_sizes[6], NP = in_sizes[7];
  const int B  = out_size;
  const int KC = in_sizes[0] / NC;                 // 74
  const int cshift = __builtin_ctz(NC / 256), cfine = NC / 256;
  const int pshift = __builtin_ctz(NP / 256), pfine = NP / 256;
  const int HN = 256 * NBLK;

  char* ws = (char*)d_ws;
  size_t off = 0;
  auto alloc = [&](size_t bytes) -> void* {
    void* p = ws + off;
    off += (bytes + 255) & ~(size_t)255;
    return p;
  };

  int* H0 = (int*)alloc((size_t)HN * 4);
  int* H1 = (int*)alloc((size_t)HN * 4);
  int* H2 = (int*)alloc((size_t)HN * 4);
  int* H3 = (int*)alloc((size_t)HN * 4);
  int* H4 = (int*)alloc((size_t)HN * 4);
  int* H5 = (int*)alloc((size_t)HN * 4);
  int* partH = (int*)alloc((size_t)6 * 32 * 4);
  unsigned short* tmps_c = (unsigned short*)alloc((size_t)EC * 2);
  unsigned short* tmps_p = (unsigned short*)alloc((size_t)EP * 2);
  unsigned int* tmpe_c = (unsigned int*)alloc((size_t)EC * 4);
  unsigned int* tmpe_p = (unsigned int*)alloc((size_t)EP * 4);
  float* c_ns = (float*)alloc((size_t)NC * 4);
  float* c_nd = (float*)alloc((size_t)NC * 4);
  float* p_ns = (float*)alloc((size_t)NP * 4);
  float* p_nd = (float*)alloc((size_t)NP * 4);
  int* c_rowptr = (int*)alloc((size_t)(NC + 1) * 4);
  int* p_rowptr = (int*)alloc((size_t)(NP + 1) * 4);
  int* c_col   = (int*)alloc((size_t)EC * 4);
  int* p_col   = (int*)alloc((size_t)EP * 4);
  int* c_perm = (int*)alloc((size_t)NC * 4);
  int* p_perm = (int*)alloc((size_t)NP * 4);
  __half* c_h  = (__half*)alloc((size_t)NC * D * 2);
  __half* c_m1 = (__half*)alloc((size_t)NC * D * 2);
  __half* c_m2 = (__half*)alloc((size_t)NC * D * 2);
  __half* p_h  = (__half*)alloc((size_t)NP * D * 2);
  __half* p_m1 = (__half*)alloc((size_t)NP * D * 2);
  __half* p_m2 = (__half*)alloc((size_t)NP * D * 2);
  _Float16* wp_p1 = (_Float16*)alloc((size_t)32 * 1024);
  _Float16* wp_c1 = (_Float16*)alloc((size_t)32 * 1024);
  _Float16* wp_p2 = (_Float16*)alloc((size_t)32 * 1024);
  _Float16* wp_c2 = (_Float16*)alloc((size_t)32 * 1024);
  (void)ws_size; (void)n_in;

  // 1) six 256-bin histograms + W fragment packing (one launch)
  {
    HW6 P = {{{c_src, EC, cshift, H0}, {c_dst, EC, cshift, H1}, {c_gid, NC, 0, H2},
              {p_src, EP, pshift, H3}, {p_dst, EP, pshift, H4}, {p_gid, NP, 0, H5}},
             {{Wp1, wp_p1, D}, {Wc1, wp_c1, KC}, {Wp2, wp_p2, D}, {Wc2, wp_c2, D}}};
    k_hist_all<<<dim3(NBLK, 7), 256, 0, stream>>>(P);
  }
  // 2) scan the six H arrays in place
  {
    SP6 Pp = {{{H0, HN, partH + 0}, {H1, HN, partH + 32}, {H2, HN, partH + 64},
               {H3, HN, partH + 96}, {H4, HN, partH + 128}, {H5, HN, partH + 160}}};
    k_scan_part_all<<<dim3(16, 6), 256, 0, stream>>>(Pp);
    SD6 Pd = {{{H0, HN, partH + 0, H0, nullptr}, {H1, HN, partH + 32, H1, nullptr},
               {H2, HN, partH + 64, H2, nullptr}, {H3, HN, partH + 96, H3, nullptr},
               {H4, HN, partH + 128, H4, nullptr}, {H5, HN, partH + 160, H5, nullptr}}};
    k_scan_down_all<<<dim3(16, 6), 256, 0, stream>>>(Pd);
  }
  // 3) level-1 scatters (packed edge sorts + gid inverse-permutations)
  {
    Sc4 P = {{{c_src, c_dst, EC, cshift, cfine - 1, H0, H1, tmps_c, nullptr, tmpe_c, 0},
              {p_src, p_dst, EP, pshift, pfine - 1, H3, H4, tmps_p, nullptr, tmpe_p, 0},
              {c_gid, nullptr, NC, 0, 0, H2, nullptr, nullptr, c_perm, nullptr, 1},
              {p_gid, nullptr, NP, 0, 0, H5, nullptr, nullptr, p_perm, nullptr, 1}}};
    k_scatter_all<<<dim3(NBLK, 4), 256, 0, stream>>>(P);
  }
  // 4) fused level-2: counts -> ns / (rowptr, nd, col)
  {
    FZ PF = {{{tmps_c, H0, EC, cfine, c_ns}, {tmps_p, H3, EP, pfine, p_ns}},
             {{tmpe_c, H1, EC, cfine, c_rowptr, c_col, c_nd, NC},
              {tmpe_p, H4, EP, pfine, p_rowptr, p_col, p_nd, NP}}};
    k_l2fused<<<dim3(NBLK, 4), 256, 0, stream>>>(PF);
  }

  // ---- towers (flattened grids: protein first) ----
  const int gnb = NP / 128 + NC / 128;
  const int ntot = NP + NC;
  const int anb = min((ntot + 3) / 4, 8192);   // grid-stride persistent waves
  {
    GemP P = {{{protein_feat, p_ns, wp_p1, p_h, D, 0},
               {compound_feat, c_ns, wp_c1, c_h, KC, 0}}, NP / 128};
    k_nl_gemm<<<gnb, 512, 0, stream>>>(P);
  }
  {
    AggP P = {{{p_h, p_rowptr, p_col, p_nd, bp1, nullptr, p_m1, 1},
               {c_h, c_rowptr, c_col, c_nd, bc1, nullptr, c_m1, 1}}, NP, ntot};
    k_aggregate<<<anb, 256, 0, stream>>>(P);
  }
  {
    GemP P = {{{p_m1, p_ns, wp_p2, p_h, D, 1}, {c_m1, c_ns, wp_c2, c_h, D, 1}}, NP / 128};
    k_nl_gemm<<<gnb, 512, 0, stream>>>(P);
  }
  {
    // layer-2 aggregate writes m2 rows permuted into graph-sorted order
    AggP P = {{{p_h, p_rowptr, p_col, p_nd, bp2, p_perm, p_m2, 1},
               {c_h, c_rowptr, c_col, c_nd, bc2, c_perm, c_m2, 1}}, NP, ntot};
    k_aggregate<<<anb, 256, 0, stream>>>(P);
  }
  // 5) fused readout: means + predictor MLP
  {
    HeadP PH = {c_m2, H2, NC, p_m2, H5, NP, Wf1, bf1, Wf2, bf2, out};
    k_head<<<B, 256, 0, stream>>>(PH);
  }
}